// Round 6
// baseline (237.420 us; speedup 1.0000x reference)
//
#include <hip/hip_runtime.h>
#include <math.h>

#define L_SEQ 4096
#define DMODEL 1024
#define DINNER 1024
#define DSTATE 64
#define NH 32
#define HD 32
#define CONVD 1152   // D_INNER + 2*D_STATE
#define DPROJ2 2272  // 2*D_INNER + 2*D_STATE + NH + IDX_DIM(k fused)
#define KOFF 2208    // column offset of fused k block in zx
#define QC 128
#define NC 32

#define NEG_FILL (-1e30f)

typedef __attribute__((ext_vector_type(8))) short short8;
typedef __attribute__((ext_vector_type(4))) float f32x4;
typedef unsigned short u16;

__device__ __forceinline__ u16 f2bf(float f) {
  unsigned int u = __float_as_uint(f);
  unsigned int r = (u + 0x7fffu + ((u >> 16) & 1u)) >> 16;  // RNE
  return (u16)r;
}
__device__ __forceinline__ float bf2f(u16 b) {
  unsigned int u = ((unsigned int)b) << 16;
  return __uint_as_float(u);
}
__device__ __forceinline__ short8 pack8(float4 a, float4 b) {
  short8 v;
  v[0] = (short)f2bf(a.x); v[1] = (short)f2bf(a.y);
  v[2] = (short)f2bf(a.z); v[3] = (short)f2bf(a.w);
  v[4] = (short)f2bf(b.x); v[5] = (short)f2bf(b.y);
  v[6] = (short)f2bf(b.z); v[7] = (short)f2bf(b.w);
  return v;
}

__device__ __forceinline__ void g2l16(const void* g, void* l) {
  __builtin_amdgcn_global_load_lds(
      (const __attribute__((address_space(1))) unsigned int*)g,
      (__attribute__((address_space(3))) unsigned int*)l, 16, 0, 0);
}

// ---------------------------------------------------------------------------
// All input casts + W_out transpose-cast in ONE launch.
// ---------------------------------------------------------------------------
#define CAST_N0 (L_SEQ * DMODEL / 8)      // 524288
#define CAST_N1 (2208 * DMODEL / 8)       // 282624
#define CAST_N2 (64 * DMODEL / 8)        // 8192
#define CAST_TOTAL (CAST_N0 + CAST_N1 + 2 * CAST_N2)  // 823296 = 3216*256
#define CAST_BLKS (CAST_TOTAL / 256)      // 3216
__global__ __launch_bounds__(256) void cast_tr_k(const float* __restrict__ x,
                                                 const float* __restrict__ W_in,
                                                 const float* __restrict__ W_k,
                                                 const float* __restrict__ W_q,
                                                 const float* __restrict__ W_out,
                                                 u16* __restrict__ x_bf,
                                                 u16* __restrict__ Wcat,
                                                 u16* __restrict__ Wq_bf,
                                                 u16* __restrict__ WoutT) {
  __shared__ float tile[64][65];
  int bid = blockIdx.x;
  if (bid < CAST_BLKS) {
    int gid = bid * 256 + threadIdx.x;
    const float* src;
    u16* dst;
    int i;
    if (gid < CAST_N0) { src = x; dst = x_bf; i = gid; }
    else if (gid < CAST_N0 + CAST_N1) { src = W_in; dst = Wcat; i = gid - CAST_N0; }
    else if (gid < CAST_N0 + CAST_N1 + CAST_N2) {
      src = W_k; dst = Wcat + (size_t)2208 * DMODEL; i = gid - CAST_N0 - CAST_N1;
    } else { src = W_q; dst = Wq_bf; i = gid - CAST_N0 - CAST_N1 - CAST_N2; }
    i *= 8;
    float4 f0 = *(const float4*)(src + i);
    float4 f1 = *(const float4*)(src + i + 4);
    *(short8*)(dst + i) = pack8(f0, f1);
    return;
  }
  // transpose-cast blocks: WoutT[j, m] = bf16(W_out[m, j]), 64x64 tiles
  bid -= CAST_BLKS;
  int bx = bid & 15, by = bid >> 4;
  int tx = threadIdx.x & 63, ty = threadIdx.x >> 6;
#pragma unroll
  for (int k = 0; k < 16; k++) {
    int r = ty + k * 4;
    tile[r][tx] = W_out[(size_t)(by * 64 + r) * 1024 + bx * 64 + tx];
  }
  __syncthreads();
#pragma unroll
  for (int k = 0; k < 16; k++) {
    int r = ty + k * 4;
    WoutT[(size_t)(bx * 64 + r) * 1024 + by * 64 + tx] = f2bf(tile[tx][r]);
  }
}

// ---------------------------------------------------------------------------
// Main GEMM (blocks [0,576)): zx = x @ [W_in; W_k]^T, 128x128 tile, BK=64.
// z-tiles (n0<1024) get silu() applied at write (yout consumes the gate
// directly); k-block cols (>=KOFF) are routed to the dense kd buffer.
// Blocks [576, 592): Wqo[i,j] = (W_q @ W_out)[i,j] * norm_w[j].
// ---------------------------------------------------------------------------
#define GEMM_BLKS 576  // (4096/128) * (2304/128) = 32 * 18
__global__ __launch_bounds__(256) void gemm_wqo_k(const u16* __restrict__ A,
                                                  const u16* __restrict__ B,
                                                  u16* __restrict__ Cbf,
                                                  u16* __restrict__ kd,
                                                  const u16* __restrict__ Wq,
                                                  const u16* __restrict__ WoutT,
                                                  const float* __restrict__ nw,
                                                  u16* __restrict__ Wqo) {
  __shared__ u16 As[128 * 64];  // 16 KB
  __shared__ u16 Bs[128 * 64];  // 16 KB
  const int tid = threadIdx.x;
  const int wave = tid >> 6, lane = tid & 63;
  const int l15 = lane & 15, quad = lane >> 4;
  const int wg = blockIdx.x;
  if (wg >= GEMM_BLKS) {  // ---- wqo branch ----
    const int j0 = (wg - GEMM_BLKS) * 64;
    f32x4 acc[4] = {};
    for (int kk = 0; kk < 32; kk++) {
      short8 b = *(const short8*)(WoutT + (size_t)(j0 + wave * 16 + l15) * 1024 + kk * 32 + quad * 8);
#pragma unroll
      for (int mi = 0; mi < 4; mi++) {
        short8 a = *(const short8*)(Wq + (size_t)(mi * 16 + l15) * 1024 + kk * 32 + quad * 8);
        acc[mi] = __builtin_amdgcn_mfma_f32_16x16x32_bf16(a, b, acc[mi], 0, 0, 0);
      }
    }
    int col = j0 + wave * 16 + l15;
    float w = nw[col];
#pragma unroll
    for (int mi = 0; mi < 4; mi++)
#pragma unroll
      for (int r = 0; r < 4; r++) {
        int i = mi * 16 + quad * 4 + r;
        Wqo[(size_t)i * 1024 + col] = f2bf(acc[mi][r] * w);
      }
    return;
  }
  // ---- main gemm ----
  const int N = DPROJ2, K = DMODEL;
  const int m0 = (wg & 31) * 128, n0 = (wg >> 5) * 128;
  const int wm = (wave >> 1) * 64, wn = (wave & 1) * 64;
  const bool dosilu = (n0 < 1024);  // z block: tile-uniform

  const u16* aptr[4];
  const u16* bptr[4];
  char *ldsA[4], *ldsB[4];
#pragma unroll
  for (int b = 0; b < 4; b++) {
    int ch = b * 256 + tid;
    int row = ch >> 3, q = (ch & 7) ^ (row & 7);
    aptr[b] = A + (size_t)(m0 + row) * K + q * 8;
    int bn = min(n0 + row, N - 1);
    bptr[b] = B + (size_t)bn * K + q * 8;
    ldsA[b] = (char*)As + b * 4096 + wave * 1024;
    ldsB[b] = (char*)Bs + b * 4096 + wave * 1024;
  }

  int offA[2][4], offB[2][4];
#pragma unroll
  for (int kk = 0; kk < 2; kk++)
#pragma unroll
    for (int i = 0; i < 4; i++) {
      int ra = wm + i * 16 + l15;
      offA[kk][i] = ra * 64 + ((kk * 4 + quad) ^ (ra & 7)) * 8;
      int rb = wn + i * 16 + l15;
      offB[kk][i] = rb * 64 + ((kk * 4 + quad) ^ (rb & 7)) * 8;
    }

  f32x4 acc[4][4] = {};
  for (int k0 = 0; k0 < K; k0 += 64) {
#pragma unroll
    for (int b = 0; b < 4; b++) g2l16(aptr[b] + k0, ldsA[b]);
#pragma unroll
    for (int b = 0; b < 4; b++) g2l16(bptr[b] + k0, ldsB[b]);
    __builtin_amdgcn_s_waitcnt(0);
    __syncthreads();
#pragma unroll
    for (int kk = 0; kk < 2; kk++) {
      short8 af[4], bfr[4];
#pragma unroll
      for (int i = 0; i < 4; i++) af[i] = *(const short8*)(As + offA[kk][i]);
#pragma unroll
      for (int j = 0; j < 4; j++) bfr[j] = *(const short8*)(Bs + offB[kk][j]);
#pragma unroll
      for (int mi = 0; mi < 4; mi++)
#pragma unroll
        for (int ni = 0; ni < 4; ni++)
          acc[mi][ni] = __builtin_amdgcn_mfma_f32_16x16x32_bf16(af[mi], bfr[ni],
                                                                acc[mi][ni], 0, 0, 0);
    }
    __syncthreads();
  }
#pragma unroll
  for (int mi = 0; mi < 4; mi++)
#pragma unroll
    for (int r = 0; r < 4; r++) {
      int grow = m0 + wm + mi * 16 + quad * 4 + r;
#pragma unroll
      for (int ni = 0; ni < 4; ni++) {
        int gcol = n0 + wn + ni * 16 + l15;
        float v = acc[mi][ni][r];
        if (dosilu) v = v / (1.f + expf(-v));
        u16 bv = f2bf(v);
        if (gcol >= KOFF) {
          if (gcol < N) kd[(size_t)grow * 64 + gcol - KOFF] = bv;
        } else {
          Cbf[(size_t)grow * N + gcol] = bv;
        }
      }
    }
}

// ---------------------------------------------------------------------------
// Split-K bf16 MFMA (N=64): P[ks][M,64] = A[M,Kslab] * B[64,Kslab]^T
// ---------------------------------------------------------------------------
__global__ __launch_bounds__(256) void splitk64(const u16* __restrict__ A,
                                                const u16* __restrict__ B,
                                                float* __restrict__ P,
                                                int M, int K) {
  __shared__ u16 As[128 * 32];
  __shared__ u16 Bs[64 * 32];
  const int tid = threadIdx.x;
  const int wave = tid >> 6, lane = tid & 63;
  const int m0 = blockIdx.x * 128;
  const int ks = blockIdx.y;
  const int wm = (wave >> 1) * 64, wn = (wave & 1) * 32;
  const int l15 = lane & 15, quad = lane >> 4;

  const int c0 = tid, c1 = 256 + tid;
  const int r0 = c0 >> 2, q0 = (c0 & 3) ^ ((r0 >> 1) & 3);
  const int r1 = c1 >> 2, q1 = (c1 & 3) ^ ((r1 >> 1) & 3);
  const int rb = tid >> 2, qb = (tid & 3) ^ ((rb >> 1) & 3);
  const u16* a0 = A + (size_t)(m0 + r0) * K + q0 * 8;
  const u16* a1 = A + (size_t)(m0 + r1) * K + q1 * 8;
  const u16* bptr = B + (size_t)rb * K + qb * 8;
  char* ldsA0 = (char*)As + wave * 1024;
  char* ldsA1 = (char*)As + 4096 + wave * 1024;
  char* ldsB = (char*)Bs + wave * 1024;

  int offA[4], offB[2];
#pragma unroll
  for (int i = 0; i < 4; i++) {
    int ra = wm + i * 16 + l15;
    offA[i] = ra * 32 + (quad ^ ((ra >> 1) & 3)) * 8;
  }
#pragma unroll
  for (int j = 0; j < 2; j++) {
    int rr = wn + j * 16 + l15;
    offB[j] = rr * 32 + (quad ^ ((rr >> 1) & 3)) * 8;
  }

  f32x4 acc[4][2] = {};
  const int kbeg = ks * 128;
  for (int k0 = kbeg; k0 < kbeg + 128; k0 += 32) {
    g2l16(a0 + k0, ldsA0);
    g2l16(a1 + k0, ldsA1);
    g2l16(bptr + k0, ldsB);
    __builtin_amdgcn_s_waitcnt(0);
    __syncthreads();
    short8 af[4], bfr[2];
#pragma unroll
    for (int i = 0; i < 4; i++) af[i] = *(const short8*)(As + offA[i]);
#pragma unroll
    for (int j = 0; j < 2; j++) bfr[j] = *(const short8*)(Bs + offB[j]);
#pragma unroll
    for (int mi = 0; mi < 4; mi++)
#pragma unroll
      for (int ni = 0; ni < 2; ni++)
        acc[mi][ni] = __builtin_amdgcn_mfma_f32_16x16x32_bf16(af[mi], bfr[ni],
                                                              acc[mi][ni], 0, 0, 0);
    __syncthreads();
  }
  float* Pp = P + (size_t)ks * M * 64;
#pragma unroll
  for (int mi = 0; mi < 4; mi++)
#pragma unroll
    for (int r = 0; r < 4; r++) {
      int grow = m0 + wm + mi * 16 + quad * 4 + r;
#pragma unroll
      for (int ni = 0; ni < 2; ni++)
        Pp[(size_t)grow * 64 + wn + ni * 16 + l15] = acc[mi][ni][r];
    }
}

// reduce split-K partials + folded RMSNorm row scale + 1/sqrt(64) score scale.
__global__ __launch_bounds__(256) void reduce8_k(const float* __restrict__ P,
                                                 const float* __restrict__ ssq,
                                                 u16* __restrict__ out, int n) {
  int i = blockIdx.x * 256 + threadIdx.x;
  if (i >= n) return;
  float s = 0.f;
#pragma unroll
  for (int ks = 0; ks < 8; ks++) s += P[(size_t)ks * n + i];
  float sc = rsqrtf(ssq[i >> 6] * (1.f / 1024.f) + 1e-5f) * 0.125f;
  out[i] = f2bf(s * sc);
}

// ---------------------------------------------------------------------------
// conv1d+SiLU (blocks [0,2304)), dt softplus + cumsum + ssq zero (blocks
// [2304,2560)). (kd densify removed: gemm writes kd directly.)
// ---------------------------------------------------------------------------
#define CONVB 2304  // 256 t-blocks * 9 cg-blocks
__global__ __launch_bounds__(256) void conv_dt_k(const u16* __restrict__ zx,
                                                 const float* __restrict__ cw,
                                                 const float* __restrict__ cb,
                                                 u16* __restrict__ xbc,
                                                 const float* __restrict__ dt_bias,
                                                 const float* __restrict__ A_log,
                                                 float* __restrict__ dtsp,
                                                 float* __restrict__ aL,
                                                 float* __restrict__ ssq) {
  int bid = blockIdx.x, tid = threadIdx.x;
  if (bid < CONVB) {
    int tblk = bid / 9, cgb = bid - tblk * 9;
    int t = tblk * 16 + (tid >> 4);
    int c0 = (cgb * 16 + (tid & 15)) * 8;
    float acc[8];
#pragma unroll
    for (int j = 0; j < 8; j++) acc[j] = cb[c0 + j];
    float wv[8][4];
#pragma unroll
    for (int j = 0; j < 8; j++) {
      float4 w4 = *(const float4*)(cw + (c0 + j) * 4);
      wv[j][0] = w4.x; wv[j][1] = w4.y; wv[j][2] = w4.z; wv[j][3] = w4.w;
    }
#pragma unroll
    for (int k = 0; k < 4; k++) {
      int s = t - 3 + k;
      if (s >= 0) {
        short8 v = *(const short8*)(zx + (size_t)s * DPROJ2 + DINNER + c0);
#pragma unroll
        for (int j = 0; j < 8; j++) acc[j] += bf2f((u16)v[j]) * wv[j][k];
      }
    }
    short8 o;
#pragma unroll
    for (int j = 0; j < 8; j++) o[j] = (short)f2bf(acc[j] / (1.f + expf(-acc[j])));
    *(short8*)(xbc + (size_t)t * CONVD + c0) = o;
    return;
  }
  int dblk = bid - CONVB;  // 0..255
  if (tid < 16) ssq[dblk * 16 + tid] = 0.f;
  int w = tid >> 6, lane = tid & 63;
  int idx = dblk * 4 + w;  // 0..1023
  int h = idx & 31, c = idx >> 5;
  float negA = -expf(A_log[h]);
  float bias = dt_bias[h];
  float carry = 0.f;
#pragma unroll
  for (int seg = 0; seg < 2; seg++) {
    int t = c * QC + seg * 64 + lane;
    float xv = bf2f(zx[(size_t)t * DPROJ2 + 2176 + h]) + bias;
    float sp = (xv > 20.f) ? xv : log1pf(expf(xv));
    dtsp[(size_t)t * 32 + h] = sp;
    float v = sp * negA;
#pragma unroll
    for (int off = 1; off < 64; off <<= 1) {
      float u = __shfl_up(v, off, 64);
      if (lane >= off) v += u;
    }
    aL[(size_t)t * 32 + h] = carry + v;
    carry += __shfl(v, 63, 64);
  }
}

// ---------------------------------------------------------------------------
// Chunk states via MFMA (blocks [0,1024)), G = C·B^T (blocks [1024,1056)),
// fully-masked score-tile fills (blocks [1056,1552)). S and G stored bf16.
// ---------------------------------------------------------------------------
__global__ __launch_bounds__(256) void csg_k(const u16* __restrict__ xbc,
                                             const float* __restrict__ dtsp,
                                             const float* __restrict__ aL,
                                             u16* __restrict__ S,
                                             u16* __restrict__ G,
                                             float* __restrict__ out) {
  int tid = threadIdx.x;
  const int wave = tid >> 6, lane = tid & 63;
  const int l15 = lane & 15, quad = lane >> 4;
  __shared__ __align__(16) u16 sXs[32 * 136];
  __shared__ __align__(16) u16 sBT[64 * 136];
  __shared__ float scoef[QC];
  if (blockIdx.x < (unsigned)(NC * NH)) {
    int h = blockIdx.x & 31, c = blockIdx.x >> 5;
    if (tid < QC) {
      float aend = aL[(size_t)(c * QC + QC - 1) * 32 + h];
      float a = aL[(size_t)(c * QC + tid) * 32 + h];
      scoef[tid] = expf(aend - a) * dtsp[(size_t)(c * QC + tid) * 32 + h];
    }
    __syncthreads();
    for (int j = tid; j < 32 * QC / 8; j += 256) {   // scaled X^T
      int s = j & 127, p0 = (j >> 7) * 8;
      short8 v = *(const short8*)(xbc + (size_t)(c * QC + s) * CONVD + h * HD + p0);
      float cf = scoef[s];
#pragma unroll
      for (int e = 0; e < 8; e++) sXs[(p0 + e) * 136 + s] = f2bf(cf * bf2f((u16)v[e]));
    }
    for (int j = tid; j < 64 * QC / 8; j += 256) {   // B^T
      int s = j & 127, n0 = (j >> 7) * 8;
      short8 v = *(const short8*)(xbc + (size_t)(c * QC + s) * CONVD + DINNER + n0);
#pragma unroll
      for (int e = 0; e < 8; e++) sBT[(n0 + e) * 136 + s] = (u16)v[e];
    }
    __syncthreads();
    f32x4 acc[2] = {};
#pragma unroll
    for (int kk = 0; kk < 4; kk++) {
      short8 b = *(const short8*)(sBT + (wave * 16 + l15) * 136 + kk * 32 + quad * 8);
#pragma unroll
      for (int i = 0; i < 2; i++) {
        short8 a = *(const short8*)(sXs + (i * 16 + l15) * 136 + kk * 32 + quad * 8);
        acc[i] = __builtin_amdgcn_mfma_f32_16x16x32_bf16(a, b, acc[i], 0, 0, 0);
      }
    }
    u16* Sb = S + ((size_t)c * 32 + h) * 2048;
#pragma unroll
    for (int i = 0; i < 2; i++)
#pragma unroll
      for (int r = 0; r < 4; r++) {
        int p = i * 16 + quad * 4 + r;
        Sb[p * 64 + wave * 16 + l15] = f2bf(acc[i][r]);
      }
    return;
  }
  if (blockIdx.x < (unsigned)(NC * NH + NC)) {
    // G = C B^T, direct bf16 global frag loads
    int c = blockIdx.x - NC * NH;
    const int wm = (wave >> 1) * 64, wn = (wave & 1) * 64;
    f32x4 acc[4][4] = {};
#pragma unroll
    for (int kk = 0; kk < 2; kk++) {
      short8 a[4], b[4];
#pragma unroll
      for (int i = 0; i < 4; i++) {
        int t = wm + i * 16 + l15;
        a[i] = *(const short8*)(xbc + (size_t)(c * QC + t) * CONVD + DINNER + DSTATE + kk * 32 + quad * 8);
        int s = wn + i * 16 + l15;
        b[i] = *(const short8*)(xbc + (size_t)(c * QC + s) * CONVD + DINNER + kk * 32 + quad * 8);
      }
#pragma unroll
      for (int mi = 0; mi < 4; mi++)
#pragma unroll
        for (int ni = 0; ni < 4; ni++)
          acc[mi][ni] = __builtin_amdgcn_mfma_f32_16x16x32_bf16(a[mi], b[ni],
                                                                acc[mi][ni], 0, 0, 0);
    }
    u16* Gb = G + (size_t)c * QC * QC;
#pragma unroll
    for (int mi = 0; mi < 4; mi++)
#pragma unroll
      for (int r = 0; r < 4; r++) {
        int t = wm + mi * 16 + quad * 4 + r;
#pragma unroll
        for (int ni = 0; ni < 4; ni++)
          Gb[(size_t)t * QC + wn + ni * 16 + l15] = f2bf(acc[mi][ni][r]);
      }
    return;
  }
  // fully-masked score tiles: enumerate {(by,bx): bx > by} via 16x31 rect
  int f = blockIdx.x - (NC * NH + NC);  // 0..495
  int u = f / 31, v = f - u * 31;
  int by, bx;
  if (v >= u) { by = u; bx = v + 1; }
  else { by = 31 - u; bx = 32 - u + v; }
  int m0 = by * 128, n0 = bx * 128;
  f32x4 fl = {NEG_FILL, NEG_FILL, NEG_FILL, NEG_FILL};
  for (int i = tid; i < 128 * 32; i += 256) {
    int row = i >> 5, c4 = (i & 31) << 2;
    __builtin_nontemporal_store(fl, (f32x4*)(out + (size_t)(m0 + row) * L_SEQ + n0 + c4));
  }
}

// ---------------------------------------------------------------------------
// Inter-chunk scan; S bf16 in, fp32 accumulate, Hinit bf16 out.
// ---------------------------------------------------------------------------
__global__ __launch_bounds__(256) void state_scan_k(const u16* __restrict__ S,
                                                    const float* __restrict__ aL,
                                                    u16* __restrict__ Hinit) {
  int idx = blockIdx.x * 256 + threadIdx.x;
  int h = idx >> 11, rem = idx & 2047;
  float E = 0.f;
#pragma unroll
  for (int c = 0; c < NC; c++) {
    size_t o = ((size_t)c * 32 + h) * 2048 + rem;
    Hinit[o] = f2bf(E);
    float dec = expf(aL[(size_t)(c * QC + QC - 1) * 32 + h]);
    E = E * dec + bf2f(S[o]);
  }
}

// ---------------------------------------------------------------------------
// yout v3: v1 structure (1024 blocks, full chunk) + VALU trims:
//   - se[t] = exp(a_t) computed once per row in prologue (was 8 expf/thread)
//   - gate = silu(z) read pre-computed from zx (silu folded into gemm),
//     staged via vectorized short8 copies (was 16 scalar z loads/thread)
// ---------------------------------------------------------------------------
__global__ __launch_bounds__(256) void yout_mfma(const u16* __restrict__ xbc,
                                                 const float* __restrict__ dtsp,
                                                 const float* __restrict__ aL,
                                                 const u16* __restrict__ G,
                                                 const u16* __restrict__ Hinit,
                                                 const float* __restrict__ Dv,
                                                 const u16* __restrict__ zx,
                                                 float* __restrict__ ssq,
                                                 u16* __restrict__ y) {
  int h = blockIdx.x & 31, c = blockIdx.x >> 5;
  int tid = threadIdx.x;
  __shared__ __align__(16) u16 sXT[32 * 136];
  __shared__ float sa[QC];
  __shared__ float sd[QC];
  __shared__ float se[QC];
  __shared__ __align__(16) u16 sgate[QC][32];

  if (tid < QC) {
    float a_ = aL[(size_t)(c * QC + tid) * 32 + h];
    sa[tid] = a_;
    se[tid] = expf(a_);
    sd[tid] = dtsp[(size_t)(c * QC + tid) * 32 + h];
  }
  for (int j = tid; j < 512; j += 256) {  // gate copy (silu pre-applied)
    int t = j >> 2, p0 = (j & 3) * 8;
    *(short8*)&sgate[t][p0] =
        *(const short8*)(zx + (size_t)(c * QC + t) * DPROJ2 + h * HD + p0);
  }
  for (int j = tid; j < 32 * QC / 8; j += 256) {
    int t = j & 127, p0 = (j >> 7) * 8;
    short8 v = *(const short8*)(xbc + (size_t)(c * QC + t) * CONVD + h * HD + p0);
#pragma unroll
    for (int e = 0; e < 8; e++) sXT[(p0 + e) * 136 + t] = (u16)v[e];
  }
  __syncthreads();

  const int wave = tid >> 6, lane = tid & 63;
  const int l15 = lane & 15, quad = lane >> 4;
  f32x4 acc1[2][2] = {};
  f32x4 acc2[2][2] = {};

#pragma unroll
  for (int kk = 0; kk < 4; kk++) {
    short8 b[2];
#pragma unroll
    for (int j = 0; j < 2; j++)
      b[j] = *(const short8*)(sXT + (j * 16 + l15) * 136 + kk * 32 + quad * 8);
#pragma unroll
    for (int i = 0; i < 2; i++) {
      int rmax = wave * 32 + i * 16 + 15;
      if (kk * 32 > rmax) continue;
      int m = wave * 32 + i * 16 + l15;
      float am = sa[m];
      short8 g8 = *(const short8*)(G + (size_t)c * QC * QC + (size_t)m * QC + kk * 32 + quad * 8);
      int s0 = kk * 32 + quad * 8;
      short8 a;
#pragma unroll
      for (int j2 = 0; j2 < 8; j2++) {
        int s = s0 + j2;
        float w = 0.f;
        if (s <= m) w = expf(am - sa[s]) * sd[s] * bf2f((u16)g8[j2]);
        a[j2] = (short)f2bf(w);
      }
#pragma unroll
      for (int j = 0; j < 2; j++)
        acc1[i][j] = __builtin_amdgcn_mfma_f32_16x16x32_bf16(a, b[j], acc1[i][j], 0, 0, 0);
    }
  }

  const u16* Hbase = Hinit + ((size_t)c * 32 + h) * 2048;
#pragma unroll
  for (int kk = 0; kk < 2; kk++) {
    short8 b[2];
#pragma unroll
    for (int j = 0; j < 2; j++)
      b[j] = *(const short8*)(Hbase + (size_t)(j * 16 + l15) * 64 + kk * 32 + quad * 8);
#pragma unroll
    for (int i = 0; i < 2; i++) {
      int t = wave * 32 + i * 16 + l15;
      short8 a = *(const short8*)(xbc + (size_t)(c * QC + t) * CONVD + DINNER + DSTATE + kk * 32 + quad * 8);
#pragma unroll
      for (int j = 0; j < 2; j++)
        acc2[i][j] = __builtin_amdgcn_mfma_f32_16x16x32_bf16(a, b[j], acc2[i][j], 0, 0, 0);
    }
  }

  float Dh = Dv[h];
#pragma unroll
  for (int i = 0; i < 2; i++) {
#pragma unroll
    for (int r = 0; r < 4; r++) {
      int t = wave * 32 + i * 16 + quad * 4 + r;
      float et = se[t];
      float part = 0.f;
#pragma unroll
      for (int j = 0; j < 2; j++) {
        int p = j * 16 + l15;
        float xv = bf2f(sXT[p * 136 + t]);
        float val = acc1[i][j][r] + et * acc2[i][j][r] + Dh * xv;
        float vg = val * bf2f(sgate[t][p]);
        part += vg * vg;
        y[(size_t)(c * QC + t) * DINNER + h * HD + p] = f2bf(vg);
      }
      part += __shfl_xor(part, 1, 64);
      part += __shfl_xor(part, 2, 64);
      part += __shfl_xor(part, 4, 64);
      part += __shfl_xor(part, 8, 64);
      if (l15 == 0) atomicAdd(ssq + c * QC + t, part);
    }
  }
}

// ---------------------------------------------------------------------------
// Causal scores via MFMA; masked tiles pre-filled by csg_k -> early return.
// Scale already folded into q (reduce8).
// ---------------------------------------------------------------------------
__global__ __launch_bounds__(256) void scores_mfma(const u16* __restrict__ q,
                                                   const u16* __restrict__ kd,
                                                   float* __restrict__ out) {
  const int m0 = blockIdx.y * 128, n0 = blockIdx.x * 128;
  if (n0 > m0 + 127) return;  // pre-filled by csg_k
  const int tid = threadIdx.x;
  const int wave = tid >> 6, lane = tid & 63;
  const int wm = (wave >> 1) * 64, wn = (wave & 1) * 64;
  const int l15 = lane & 15, quad = lane >> 4;
  f32x4 acc[4][4] = {};
#pragma unroll
  for (int kk = 0; kk < 2; kk++) {
    short8 a[4], b[4];
#pragma unroll
    for (int i = 0; i < 4; i++) {
      a[i] = *(const short8*)(q + (size_t)(m0 + wm + i * 16 + l15) * 64 + kk * 32 + quad * 8);
      b[i] = *(const short8*)(kd + (size_t)(n0 + wn + i * 16 + l15) * 64 + kk * 32 + quad * 8);
    }
#pragma unroll
    for (int mi = 0; mi < 4; mi++)
#pragma unroll
      for (int ni = 0; ni < 4; ni++)
        acc[mi][ni] = __builtin_amdgcn_mfma_f32_16x16x32_bf16(a[mi], b[ni],
                                                              acc[mi][ni], 0, 0, 0);
  }
#pragma unroll
  for (int mi = 0; mi < 4; mi++)
#pragma unroll
    for (int r = 0; r < 4; r++) {
      int row = m0 + wm + mi * 16 + quad * 4 + r;
#pragma unroll
      for (int ni = 0; ni < 4; ni++) {
        int col = n0 + wn + ni * 16 + l15;
        float val = (col <= row) ? acc[mi][ni][r] : NEG_FILL;
        __builtin_nontemporal_store(val, out + (size_t)row * L_SEQ + col);
      }
    }
}

// ---------------------------------------------------------------------------
extern "C" void kernel_launch(void* const* d_in, const int* in_sizes, int n_in,
                              void* d_out, int out_size, void* d_ws, size_t ws_size,
                              hipStream_t stream) {
  const float* x       = (const float*)d_in[0];
  const float* W_in    = (const float*)d_in[1];
  const float* conv_w  = (const float*)d_in[2];
  const float* conv_b  = (const float*)d_in[3];
  const float* dt_bias = (const float*)d_in[4];
  const float* A_log   = (const float*)d_in[5];
  const float* Dv      = (const float*)d_in[6];
  const float* norm_w  = (const float*)d_in[7];
  const float* W_out   = (const float*)d_in[8];
  const float* W_q     = (const float*)d_in[9];
  const float* W_k     = (const float*)d_in[10];
  float* out = (float*)d_out;

  char* ws = (char*)d_ws;
  size_t off = 0;
  auto alloc = [&](size_t bytes) {
    void* p = (void*)(ws + off);
    off += (bytes + 255) & ~(size_t)255;
    return p;
  };
  u16* zx_bf    = (u16*)alloc((size_t)L_SEQ * DPROJ2 * 2);
  u16* xbc_bf   = (u16*)alloc((size_t)L_SEQ * CONVD * 2);
  float* dtsp   = (float*)alloc((size_t)L_SEQ * NH * 4);
  float* aL     = (float*)alloc((size_t)L_SEQ * NH * 4);
  u16* S        = (u16*)alloc((size_t)NC * NH * HD * DSTATE * 2);
  u16* Hinit    = (u16*)alloc((size_t)NC * NH * HD * DSTATE * 2);
  u16* G        = (u16*)alloc((size_t)NC * QC * QC * 2);
  float* ssq    = (float*)alloc((size_t)L_SEQ * 4);
  u16* y1_bf    = (u16*)alloc((size_t)L_SEQ * DINNER * 2);
  u16* kd_bf    = (u16*)alloc((size_t)L_SEQ * 64 * 2);
  u16* x_bf     = (u16*)alloc((size_t)L_SEQ * DMODEL * 2);
  u16* Wcat_bf  = (u16*)alloc((size_t)DPROJ2 * DMODEL * 2);
  u16* WoutT_bf = (u16*)alloc((size_t)DMODEL * DINNER * 2);
  u16* Wq_bf    = (u16*)alloc((size_t)64 * DMODEL * 2);
  u16* Wqo_bf   = (u16*)alloc((size_t)64 * DINNER * 2);
  u16* q_bf     = (u16*)alloc((size_t)L_SEQ * 64 * 2);
  float* Pq     = (float*)alloc((size_t)8 * L_SEQ * 64 * 4);

  // 1. all casts + W_out transpose-cast
  cast_tr_k<<<dim3(CAST_BLKS + 256), 256, 0, stream>>>(x, W_in, W_k, W_q, W_out,
                                                       x_bf, Wcat_bf, Wq_bf, WoutT_bf);
  // 2. zx gemm (silu on z block, k routed to kd) + wqo fold
  gemm_wqo_k<<<dim3(GEMM_BLKS + 16), 256, 0, stream>>>(x_bf, Wcat_bf, zx_bf, kd_bf,
                                                       Wq_bf, WoutT_bf, norm_w, Wqo_bf);
  // 3. conv+silu | dt+cumsum+ssq-zero
  conv_dt_k<<<dim3(CONVB + 256), 256, 0, stream>>>(
      zx_bf, conv_w, conv_b, xbc_bf, dt_bias, A_log, dtsp, aL, ssq);
  // 4. chunk states | G | masked score-tile fills (S, G bf16)
  csg_k<<<dim3(NC * NH + NC + 496), 256, 0, stream>>>(xbc_bf, dtsp, aL, S, G, out);
  // 5. inter-chunk scan (bf16 S in, bf16 Hinit out)
  state_scan_k<<<dim3(NH * HD * DSTATE / 256), 256, 0, stream>>>(S, aL, Hinit);
  // 6. y via MFMA (v3: 1024 blocks + VALU trims), gated + ssq accumulation
  yout_mfma<<<dim3(NC * NH), 256, 0, stream>>>(xbc_bf, dtsp, aL, G, Hinit, Dv,
                                               zx_bf, ssq, y1_bf);
  // 7. q partials: split-K (short chain, full CU coverage)
  splitk64<<<dim3(L_SEQ / 128, 8), 256, 0, stream>>>(y1_bf, Wqo_bf, Pq, L_SEQ, DINNER);
  // 8. reduce + RMS row scale + 0.125
  reduce8_k<<<dim3(L_SEQ * 64 / 256), 256, 0, stream>>>(Pq, ssq, q_bf, L_SEQ * 64);
  // 9. causal scores (lower-triangle tiles only)
  scores_mfma<<<dim3(32, 32), 256, 0, stream>>>(q_bf, kd_bf, out);
}

// Round 7
// 218.522 us; speedup vs baseline: 1.0865x; 1.0865x over previous
//
#include <hip/hip_runtime.h>
#include <math.h>

#define L_SEQ 4096
#define DMODEL 1024
#define DINNER 1024
#define DSTATE 64
#define NH 32
#define HD 32
#define CONVD 1152   // D_INNER + 2*D_STATE
#define DPROJ2 2272  // 2*D_INNER + 2*D_STATE + NH + IDX_DIM(k fused)
#define KOFF 2208    // column offset of fused k block in zx
#define QC 128
#define NC 32

#define NEG_FILL (-1e30f)

typedef __attribute__((ext_vector_type(8))) short short8;
typedef __attribute__((ext_vector_type(4))) float f32x4;
typedef unsigned short u16;

__device__ __forceinline__ u16 f2bf(float f) {
  unsigned int u = __float_as_uint(f);
  unsigned int r = (u + 0x7fffu + ((u >> 16) & 1u)) >> 16;  // RNE
  return (u16)r;
}
__device__ __forceinline__ float bf2f(u16 b) {
  unsigned int u = ((unsigned int)b) << 16;
  return __uint_as_float(u);
}
__device__ __forceinline__ short8 pack8(float4 a, float4 b) {
  short8 v;
  v[0] = (short)f2bf(a.x); v[1] = (short)f2bf(a.y);
  v[2] = (short)f2bf(a.z); v[3] = (short)f2bf(a.w);
  v[4] = (short)f2bf(b.x); v[5] = (short)f2bf(b.y);
  v[6] = (short)f2bf(b.z); v[7] = (short)f2bf(b.w);
  return v;
}

__device__ __forceinline__ void g2l16(const void* g, void* l) {
  __builtin_amdgcn_global_load_lds(
      (const __attribute__((address_space(1))) unsigned int*)g,
      (__attribute__((address_space(3))) unsigned int*)l, 16, 0, 0);
}

// ---------------------------------------------------------------------------
// All input casts + W_out transpose-cast in ONE launch.
// ---------------------------------------------------------------------------
#define CAST_N0 (L_SEQ * DMODEL / 8)      // 524288
#define CAST_N1 (2208 * DMODEL / 8)       // 282624
#define CAST_N2 (64 * DMODEL / 8)         // 8192
#define CAST_TOTAL (CAST_N0 + CAST_N1 + 2 * CAST_N2)  // 823296 = 3216*256
#define CAST_BLKS (CAST_TOTAL / 256)      // 3216
__global__ __launch_bounds__(256) void cast_tr_k(const float* __restrict__ x,
                                                 const float* __restrict__ W_in,
                                                 const float* __restrict__ W_k,
                                                 const float* __restrict__ W_q,
                                                 const float* __restrict__ W_out,
                                                 u16* __restrict__ x_bf,
                                                 u16* __restrict__ Wcat,
                                                 u16* __restrict__ Wq_bf,
                                                 u16* __restrict__ WoutT) {
  __shared__ float tile[64][65];
  int bid = blockIdx.x;
  if (bid < CAST_BLKS) {
    int gid = bid * 256 + threadIdx.x;
    const float* src;
    u16* dst;
    int i;
    if (gid < CAST_N0) { src = x; dst = x_bf; i = gid; }
    else if (gid < CAST_N0 + CAST_N1) { src = W_in; dst = Wcat; i = gid - CAST_N0; }
    else if (gid < CAST_N0 + CAST_N1 + CAST_N2) {
      src = W_k; dst = Wcat + (size_t)2208 * DMODEL; i = gid - CAST_N0 - CAST_N1;
    } else { src = W_q; dst = Wq_bf; i = gid - CAST_N0 - CAST_N1 - CAST_N2; }
    i *= 8;
    float4 f0 = *(const float4*)(src + i);
    float4 f1 = *(const float4*)(src + i + 4);
    *(short8*)(dst + i) = pack8(f0, f1);
    return;
  }
  // transpose-cast blocks: WoutT[j, m] = bf16(W_out[m, j]), 64x64 tiles
  bid -= CAST_BLKS;
  int bx = bid & 15, by = bid >> 4;
  int tx = threadIdx.x & 63, ty = threadIdx.x >> 6;
#pragma unroll
  for (int k = 0; k < 16; k++) {
    int r = ty + k * 4;
    tile[r][tx] = W_out[(size_t)(by * 64 + r) * 1024 + bx * 64 + tx];
  }
  __syncthreads();
#pragma unroll
  for (int k = 0; k < 16; k++) {
    int r = ty + k * 4;
    WoutT[(size_t)(bx * 64 + r) * 1024 + by * 64 + tx] = f2bf(tile[tx][r]);
  }
}

// ---------------------------------------------------------------------------
// Main GEMM (blocks [0,576)): zx = x @ [W_in; W_k]^T, 128x128 tile, BK=64.
// Blocks [576, 592): Wqo[i,j] = (W_q @ W_out)[i,j] * norm_w[j].
// (Epilogue kept branch-free per R6 post-mortem: silu/kd folding cost +13us.)
// ---------------------------------------------------------------------------
#define GEMM_BLKS 576  // (4096/128) * (2304/128) = 32 * 18
__global__ __launch_bounds__(256) void gemm_wqo_k(const u16* __restrict__ A,
                                                  const u16* __restrict__ B,
                                                  u16* __restrict__ Cbf,
                                                  const u16* __restrict__ Wq,
                                                  const u16* __restrict__ WoutT,
                                                  const float* __restrict__ nw,
                                                  u16* __restrict__ Wqo) {
  __shared__ u16 As[128 * 64];  // 16 KB
  __shared__ u16 Bs[128 * 64];  // 16 KB
  const int tid = threadIdx.x;
  const int wave = tid >> 6, lane = tid & 63;
  const int l15 = lane & 15, quad = lane >> 4;
  const int wg = blockIdx.x;
  if (wg >= GEMM_BLKS) {  // ---- wqo branch ----
    const int j0 = (wg - GEMM_BLKS) * 64;
    f32x4 acc[4] = {};
    for (int kk = 0; kk < 32; kk++) {
      short8 b = *(const short8*)(WoutT + (size_t)(j0 + wave * 16 + l15) * 1024 + kk * 32 + quad * 8);
#pragma unroll
      for (int mi = 0; mi < 4; mi++) {
        short8 a = *(const short8*)(Wq + (size_t)(mi * 16 + l15) * 1024 + kk * 32 + quad * 8);
        acc[mi] = __builtin_amdgcn_mfma_f32_16x16x32_bf16(a, b, acc[mi], 0, 0, 0);
      }
    }
    int col = j0 + wave * 16 + l15;
    float w = nw[col];
#pragma unroll
    for (int mi = 0; mi < 4; mi++)
#pragma unroll
      for (int r = 0; r < 4; r++) {
        int i = mi * 16 + quad * 4 + r;
        Wqo[(size_t)i * 1024 + col] = f2bf(acc[mi][r] * w);
      }
    return;
  }
  // ---- main gemm ----
  const int N = DPROJ2, K = DMODEL;
  const int m0 = (wg & 31) * 128, n0 = (wg >> 5) * 128;
  const int wm = (wave >> 1) * 64, wn = (wave & 1) * 64;

  const u16* aptr[4];
  const u16* bptr[4];
  char *ldsA[4], *ldsB[4];
#pragma unroll
  for (int b = 0; b < 4; b++) {
    int ch = b * 256 + tid;
    int row = ch >> 3, q = (ch & 7) ^ (row & 7);
    aptr[b] = A + (size_t)(m0 + row) * K + q * 8;
    int bn = min(n0 + row, N - 1);
    bptr[b] = B + (size_t)bn * K + q * 8;
    ldsA[b] = (char*)As + b * 4096 + wave * 1024;
    ldsB[b] = (char*)Bs + b * 4096 + wave * 1024;
  }

  int offA[2][4], offB[2][4];
#pragma unroll
  for (int kk = 0; kk < 2; kk++)
#pragma unroll
    for (int i = 0; i < 4; i++) {
      int ra = wm + i * 16 + l15;
      offA[kk][i] = ra * 64 + ((kk * 4 + quad) ^ (ra & 7)) * 8;
      int rb = wn + i * 16 + l15;
      offB[kk][i] = rb * 64 + ((kk * 4 + quad) ^ (rb & 7)) * 8;
    }

  f32x4 acc[4][4] = {};
  for (int k0 = 0; k0 < K; k0 += 64) {
#pragma unroll
    for (int b = 0; b < 4; b++) g2l16(aptr[b] + k0, ldsA[b]);
#pragma unroll
    for (int b = 0; b < 4; b++) g2l16(bptr[b] + k0, ldsB[b]);
    __builtin_amdgcn_s_waitcnt(0);
    __syncthreads();
#pragma unroll
    for (int kk = 0; kk < 2; kk++) {
      short8 af[4], bfr[4];
#pragma unroll
      for (int i = 0; i < 4; i++) af[i] = *(const short8*)(As + offA[kk][i]);
#pragma unroll
      for (int j = 0; j < 4; j++) bfr[j] = *(const short8*)(Bs + offB[kk][j]);
#pragma unroll
      for (int mi = 0; mi < 4; mi++)
#pragma unroll
        for (int ni = 0; ni < 4; ni++)
          acc[mi][ni] = __builtin_amdgcn_mfma_f32_16x16x32_bf16(af[mi], bfr[ni],
                                                                acc[mi][ni], 0, 0, 0);
    }
    __syncthreads();
  }
#pragma unroll
  for (int mi = 0; mi < 4; mi++)
#pragma unroll
    for (int r = 0; r < 4; r++) {
      int grow = m0 + wm + mi * 16 + quad * 4 + r;
#pragma unroll
      for (int ni = 0; ni < 4; ni++) {
        int gcol = n0 + wn + ni * 16 + l15;
        if (gcol < N) Cbf[(size_t)grow * N + gcol] = f2bf(acc[mi][ni][r]);
      }
    }
}

// ---------------------------------------------------------------------------
// Split-K bf16 MFMA (N=64): P[ks][M,64] = A[M,Kslab] * B[64,Kslab]^T
// ---------------------------------------------------------------------------
__global__ __launch_bounds__(256) void splitk64(const u16* __restrict__ A,
                                                const u16* __restrict__ B,
                                                float* __restrict__ P,
                                                int M, int K) {
  __shared__ u16 As[128 * 32];
  __shared__ u16 Bs[64 * 32];
  const int tid = threadIdx.x;
  const int wave = tid >> 6, lane = tid & 63;
  const int m0 = blockIdx.x * 128;
  const int ks = blockIdx.y;
  const int wm = (wave >> 1) * 64, wn = (wave & 1) * 32;
  const int l15 = lane & 15, quad = lane >> 4;

  const int c0 = tid, c1 = 256 + tid;
  const int r0 = c0 >> 2, q0 = (c0 & 3) ^ ((r0 >> 1) & 3);
  const int r1 = c1 >> 2, q1 = (c1 & 3) ^ ((r1 >> 1) & 3);
  const int rb = tid >> 2, qb = (tid & 3) ^ ((rb >> 1) & 3);
  const u16* a0 = A + (size_t)(m0 + r0) * K + q0 * 8;
  const u16* a1 = A + (size_t)(m0 + r1) * K + q1 * 8;
  const u16* bptr = B + (size_t)rb * K + qb * 8;
  char* ldsA0 = (char*)As + wave * 1024;
  char* ldsA1 = (char*)As + 4096 + wave * 1024;
  char* ldsB = (char*)Bs + wave * 1024;

  int offA[4], offB[2];
#pragma unroll
  for (int i = 0; i < 4; i++) {
    int ra = wm + i * 16 + l15;
    offA[i] = ra * 32 + (quad ^ ((ra >> 1) & 3)) * 8;
  }
#pragma unroll
  for (int j = 0; j < 2; j++) {
    int rr = wn + j * 16 + l15;
    offB[j] = rr * 32 + (quad ^ ((rr >> 1) & 3)) * 8;
  }

  f32x4 acc[4][2] = {};
  const int kbeg = ks * 128;
  for (int k0 = kbeg; k0 < kbeg + 128; k0 += 32) {
    g2l16(a0 + k0, ldsA0);
    g2l16(a1 + k0, ldsA1);
    g2l16(bptr + k0, ldsB);
    __builtin_amdgcn_s_waitcnt(0);
    __syncthreads();
    short8 af[4], bfr[2];
#pragma unroll
    for (int i = 0; i < 4; i++) af[i] = *(const short8*)(As + offA[i]);
#pragma unroll
    for (int j = 0; j < 2; j++) bfr[j] = *(const short8*)(Bs + offB[j]);
#pragma unroll
    for (int mi = 0; mi < 4; mi++)
#pragma unroll
      for (int ni = 0; ni < 2; ni++)
        acc[mi][ni] = __builtin_amdgcn_mfma_f32_16x16x32_bf16(af[mi], bfr[ni],
                                                              acc[mi][ni], 0, 0, 0);
    __syncthreads();
  }
  float* Pp = P + (size_t)ks * M * 64;
#pragma unroll
  for (int mi = 0; mi < 4; mi++)
#pragma unroll
    for (int r = 0; r < 4; r++) {
      int grow = m0 + wm + mi * 16 + quad * 4 + r;
#pragma unroll
      for (int ni = 0; ni < 2; ni++)
        Pp[(size_t)grow * 64 + wn + ni * 16 + l15] = acc[mi][ni][r];
    }
}

// reduce split-K partials + folded RMSNorm row scale + 1/sqrt(64) score scale.
__global__ __launch_bounds__(256) void reduce8_k(const float* __restrict__ P,
                                                 const float* __restrict__ ssq,
                                                 u16* __restrict__ out, int n) {
  int i = blockIdx.x * 256 + threadIdx.x;
  if (i >= n) return;
  float s = 0.f;
#pragma unroll
  for (int ks = 0; ks < 8; ks++) s += P[(size_t)ks * n + i];
  float sc = rsqrtf(ssq[i >> 6] * (1.f / 1024.f) + 1e-5f) * 0.125f;
  out[i] = f2bf(s * sc);
}

// ---------------------------------------------------------------------------
// conv1d+SiLU (blocks [0,2304)), k-densify (blocks [2304,2432)),
// dt softplus + cumsum + ssq zero (blocks [2432,2688)).
// ---------------------------------------------------------------------------
#define CONVB 2304  // 256 t-blocks * 9 cg-blocks
#define KDB 128
__global__ __launch_bounds__(256) void conv_dt_k(const u16* __restrict__ zx,
                                                 const float* __restrict__ cw,
                                                 const float* __restrict__ cb,
                                                 u16* __restrict__ xbc,
                                                 u16* __restrict__ kd,
                                                 const float* __restrict__ dt_bias,
                                                 const float* __restrict__ A_log,
                                                 float* __restrict__ dtsp,
                                                 float* __restrict__ aL,
                                                 float* __restrict__ ssq) {
  int bid = blockIdx.x, tid = threadIdx.x;
  if (bid < CONVB) {
    int tblk = bid / 9, cgb = bid - tblk * 9;
    int t = tblk * 16 + (tid >> 4);
    int c0 = (cgb * 16 + (tid & 15)) * 8;
    float acc[8];
#pragma unroll
    for (int j = 0; j < 8; j++) acc[j] = cb[c0 + j];
    float wv[8][4];
#pragma unroll
    for (int j = 0; j < 8; j++) {
      float4 w4 = *(const float4*)(cw + (c0 + j) * 4);
      wv[j][0] = w4.x; wv[j][1] = w4.y; wv[j][2] = w4.z; wv[j][3] = w4.w;
    }
#pragma unroll
    for (int k = 0; k < 4; k++) {
      int s = t - 3 + k;
      if (s >= 0) {
        short8 v = *(const short8*)(zx + (size_t)s * DPROJ2 + DINNER + c0);
#pragma unroll
        for (int j = 0; j < 8; j++) acc[j] += bf2f((u16)v[j]) * wv[j][k];
      }
    }
    short8 o;
#pragma unroll
    for (int j = 0; j < 8; j++) o[j] = (short)f2bf(acc[j] / (1.f + expf(-acc[j])));
    *(short8*)(xbc + (size_t)t * CONVD + c0) = o;
    return;
  }
  if (bid < CONVB + KDB) {  // densify k: kd[t, 0..64) = zx[t, KOFF..KOFF+64)
    int gid = (bid - CONVB) * 256 + tid;
    int t = gid >> 3, c0 = (gid & 7) * 8;
    *(short8*)(kd + (size_t)t * 64 + c0) =
        *(const short8*)(zx + (size_t)t * DPROJ2 + KOFF + c0);
    return;
  }
  int dblk = bid - CONVB - KDB;  // 0..255
  if (tid < 16) ssq[dblk * 16 + tid] = 0.f;
  int w = tid >> 6, lane = tid & 63;
  int idx = dblk * 4 + w;  // 0..1023
  int h = idx & 31, c = idx >> 5;
  float negA = -expf(A_log[h]);
  float bias = dt_bias[h];
  float carry = 0.f;
#pragma unroll
  for (int seg = 0; seg < 2; seg++) {
    int t = c * QC + seg * 64 + lane;
    float xv = bf2f(zx[(size_t)t * DPROJ2 + 2176 + h]) + bias;
    float sp = (xv > 20.f) ? xv : log1pf(expf(xv));
    dtsp[(size_t)t * 32 + h] = sp;
    float v = sp * negA;
#pragma unroll
    for (int off = 1; off < 64; off <<= 1) {
      float u = __shfl_up(v, off, 64);
      if (lane >= off) v += u;
    }
    aL[(size_t)t * 32 + h] = carry + v;
    carry += __shfl(v, 63, 64);
  }
}

// ---------------------------------------------------------------------------
// Chunk states via MFMA (blocks [0,1024)), G = C·B^T (blocks [1024,1056)),
// fully-masked score-tile fills (blocks [1056,1552)). S and G stored bf16.
// ---------------------------------------------------------------------------
__global__ __launch_bounds__(256) void csg_k(const u16* __restrict__ xbc,
                                             const float* __restrict__ dtsp,
                                             const float* __restrict__ aL,
                                             u16* __restrict__ S,
                                             u16* __restrict__ G,
                                             float* __restrict__ out) {
  int tid = threadIdx.x;
  const int wave = tid >> 6, lane = tid & 63;
  const int l15 = lane & 15, quad = lane >> 4;
  __shared__ __align__(16) u16 sXs[32 * 136];
  __shared__ __align__(16) u16 sBT[64 * 136];
  __shared__ float scoef[QC];
  if (blockIdx.x < (unsigned)(NC * NH)) {
    int h = blockIdx.x & 31, c = blockIdx.x >> 5;
    if (tid < QC) {
      float aend = aL[(size_t)(c * QC + QC - 1) * 32 + h];
      float a = aL[(size_t)(c * QC + tid) * 32 + h];
      scoef[tid] = expf(aend - a) * dtsp[(size_t)(c * QC + tid) * 32 + h];
    }
    __syncthreads();
    for (int j = tid; j < 32 * QC / 8; j += 256) {   // scaled X^T
      int s = j & 127, p0 = (j >> 7) * 8;
      short8 v = *(const short8*)(xbc + (size_t)(c * QC + s) * CONVD + h * HD + p0);
      float cf = scoef[s];
#pragma unroll
      for (int e = 0; e < 8; e++) sXs[(p0 + e) * 136 + s] = f2bf(cf * bf2f((u16)v[e]));
    }
    for (int j = tid; j < 64 * QC / 8; j += 256) {   // B^T
      int s = j & 127, n0 = (j >> 7) * 8;
      short8 v = *(const short8*)(xbc + (size_t)(c * QC + s) * CONVD + DINNER + n0);
#pragma unroll
      for (int e = 0; e < 8; e++) sBT[(n0 + e) * 136 + s] = (u16)v[e];
    }
    __syncthreads();
    f32x4 acc[2] = {};
#pragma unroll
    for (int kk = 0; kk < 4; kk++) {
      short8 b = *(const short8*)(sBT + (wave * 16 + l15) * 136 + kk * 32 + quad * 8);
#pragma unroll
      for (int i = 0; i < 2; i++) {
        short8 a = *(const short8*)(sXs + (i * 16 + l15) * 136 + kk * 32 + quad * 8);
        acc[i] = __builtin_amdgcn_mfma_f32_16x16x32_bf16(a, b, acc[i], 0, 0, 0);
      }
    }
    u16* Sb = S + ((size_t)c * 32 + h) * 2048;
#pragma unroll
    for (int i = 0; i < 2; i++)
#pragma unroll
      for (int r = 0; r < 4; r++) {
        int p = i * 16 + quad * 4 + r;
        Sb[p * 64 + wave * 16 + l15] = f2bf(acc[i][r]);
      }
    return;
  }
  if (blockIdx.x < (unsigned)(NC * NH + NC)) {
    // G = C B^T, direct bf16 global frag loads
    int c = blockIdx.x - NC * NH;
    const int wm = (wave >> 1) * 64, wn = (wave & 1) * 64;
    f32x4 acc[4][4] = {};
#pragma unroll
    for (int kk = 0; kk < 2; kk++) {
      short8 a[4], b[4];
#pragma unroll
      for (int i = 0; i < 4; i++) {
        int t = wm + i * 16 + l15;
        a[i] = *(const short8*)(xbc + (size_t)(c * QC + t) * CONVD + DINNER + DSTATE + kk * 32 + quad * 8);
        int s = wn + i * 16 + l15;
        b[i] = *(const short8*)(xbc + (size_t)(c * QC + s) * CONVD + DINNER + kk * 32 + quad * 8);
      }
#pragma unroll
      for (int mi = 0; mi < 4; mi++)
#pragma unroll
        for (int ni = 0; ni < 4; ni++)
          acc[mi][ni] = __builtin_amdgcn_mfma_f32_16x16x32_bf16(a[mi], b[ni],
                                                                acc[mi][ni], 0, 0, 0);
    }
    u16* Gb = G + (size_t)c * QC * QC;
#pragma unroll
    for (int mi = 0; mi < 4; mi++)
#pragma unroll
      for (int r = 0; r < 4; r++) {
        int t = wm + mi * 16 + quad * 4 + r;
#pragma unroll
        for (int ni = 0; ni < 4; ni++)
          Gb[(size_t)t * QC + wn + ni * 16 + l15] = f2bf(acc[mi][ni][r]);
      }
    return;
  }
  // fully-masked score tiles: enumerate {(by,bx): bx > by} via 16x31 rect
  int f = blockIdx.x - (NC * NH + NC);  // 0..495
  int u = f / 31, v = f - u * 31;
  int by, bx;
  if (v >= u) { by = u; bx = v + 1; }
  else { by = 31 - u; bx = 32 - u + v; }
  int m0 = by * 128, n0 = bx * 128;
  f32x4 fl = {NEG_FILL, NEG_FILL, NEG_FILL, NEG_FILL};
  for (int i = tid; i < 128 * 32; i += 256) {
    int row = i >> 5, c4 = (i & 31) << 2;
    __builtin_nontemporal_store(fl, (f32x4*)(out + (size_t)(m0 + row) * L_SEQ + n0 + c4));
  }
}

// ---------------------------------------------------------------------------
// Inter-chunk scan; S bf16 in, fp32 accumulate, Hinit bf16 out.
// ---------------------------------------------------------------------------
__global__ __launch_bounds__(256) void state_scan_k(const u16* __restrict__ S,
                                                    const float* __restrict__ aL,
                                                    u16* __restrict__ Hinit) {
  int idx = blockIdx.x * 256 + threadIdx.x;
  int h = idx >> 11, rem = idx & 2047;
  float E = 0.f;
#pragma unroll
  for (int c = 0; c < NC; c++) {
    size_t o = ((size_t)c * 32 + h) * 2048 + rem;
    Hinit[o] = f2bf(E);
    float dec = expf(aL[(size_t)(c * QC + QC - 1) * 32 + h]);
    E = E * dec + bf2f(S[o]);
  }
}

// ---------------------------------------------------------------------------
// yout (R4 v1 structure + prologue trims): 1024 blocks, full chunk.
//   - se[t] = exp(a_t) once per row in prologue (was 8 expf/thread epilogue)
//   - gate silu(z) computed in prologue from vectorized short8 z loads into
//     fp32 LDS (was 16 scalar z loads + 16 expf on the epilogue path)
// ---------------------------------------------------------------------------
__global__ __launch_bounds__(256) void yout_mfma(const u16* __restrict__ xbc,
                                                 const float* __restrict__ dtsp,
                                                 const float* __restrict__ aL,
                                                 const u16* __restrict__ G,
                                                 const u16* __restrict__ Hinit,
                                                 const float* __restrict__ Dv,
                                                 const u16* __restrict__ zx,
                                                 float* __restrict__ ssq,
                                                 u16* __restrict__ y) {
  int h = blockIdx.x & 31, c = blockIdx.x >> 5;
  int tid = threadIdx.x;
  __shared__ __align__(16) u16 sXT[32 * 136];
  __shared__ float sa[QC];
  __shared__ float sd[QC];
  __shared__ float se[QC];
  __shared__ float sgate[QC][32];

  if (tid < QC) {
    float a_ = aL[(size_t)(c * QC + tid) * 32 + h];
    sa[tid] = a_;
    se[tid] = expf(a_);
    sd[tid] = dtsp[(size_t)(c * QC + tid) * 32 + h];
  }
  for (int j = tid; j < 512; j += 256) {  // silu(z) gate, vectorized loads
    int t = j >> 2, p0 = (j & 3) * 8;
    short8 v = *(const short8*)(zx + (size_t)(c * QC + t) * DPROJ2 + h * HD + p0);
#pragma unroll
    for (int e = 0; e < 8; e++) {
      float z = bf2f((u16)v[e]);
      sgate[t][p0 + e] = z / (1.f + expf(-z));
    }
  }
  for (int j = tid; j < 32 * QC / 8; j += 256) {
    int t = j & 127, p0 = (j >> 7) * 8;
    short8 v = *(const short8*)(xbc + (size_t)(c * QC + t) * CONVD + h * HD + p0);
#pragma unroll
    for (int e = 0; e < 8; e++) sXT[(p0 + e) * 136 + t] = (u16)v[e];
  }
  __syncthreads();

  const int wave = tid >> 6, lane = tid & 63;
  const int l15 = lane & 15, quad = lane >> 4;
  f32x4 acc1[2][2] = {};
  f32x4 acc2[2][2] = {};

#pragma unroll
  for (int kk = 0; kk < 4; kk++) {
    short8 b[2];
#pragma unroll
    for (int j = 0; j < 2; j++)
      b[j] = *(const short8*)(sXT + (j * 16 + l15) * 136 + kk * 32 + quad * 8);
#pragma unroll
    for (int i = 0; i < 2; i++) {
      int rmax = wave * 32 + i * 16 + 15;
      if (kk * 32 > rmax) continue;
      int m = wave * 32 + i * 16 + l15;
      float am = sa[m];
      short8 g8 = *(const short8*)(G + (size_t)c * QC * QC + (size_t)m * QC + kk * 32 + quad * 8);
      int s0 = kk * 32 + quad * 8;
      short8 a;
#pragma unroll
      for (int j2 = 0; j2 < 8; j2++) {
        int s = s0 + j2;
        float w = 0.f;
        if (s <= m) w = expf(am - sa[s]) * sd[s] * bf2f((u16)g8[j2]);
        a[j2] = (short)f2bf(w);
      }
#pragma unroll
      for (int j = 0; j < 2; j++)
        acc1[i][j] = __builtin_amdgcn_mfma_f32_16x16x32_bf16(a, b[j], acc1[i][j], 0, 0, 0);
    }
  }

  const u16* Hbase = Hinit + ((size_t)c * 32 + h) * 2048;
#pragma unroll
  for (int kk = 0; kk < 2; kk++) {
    short8 b[2];
#pragma unroll
    for (int j = 0; j < 2; j++)
      b[j] = *(const short8*)(Hbase + (size_t)(j * 16 + l15) * 64 + kk * 32 + quad * 8);
#pragma unroll
    for (int i = 0; i < 2; i++) {
      int t = wave * 32 + i * 16 + l15;
      short8 a = *(const short8*)(xbc + (size_t)(c * QC + t) * CONVD + DINNER + DSTATE + kk * 32 + quad * 8);
#pragma unroll
      for (int j = 0; j < 2; j++)
        acc2[i][j] = __builtin_amdgcn_mfma_f32_16x16x32_bf16(a, b[j], acc2[i][j], 0, 0, 0);
    }
  }

  float Dh = Dv[h];
#pragma unroll
  for (int i = 0; i < 2; i++) {
#pragma unroll
    for (int r = 0; r < 4; r++) {
      int t = wave * 32 + i * 16 + quad * 4 + r;
      float et = se[t];
      float part = 0.f;
#pragma unroll
      for (int j = 0; j < 2; j++) {
        int p = j * 16 + l15;
        float xv = bf2f(sXT[p * 136 + t]);
        float val = acc1[i][j][r] + et * acc2[i][j][r] + Dh * xv;
        float vg = val * sgate[t][p];
        part += vg * vg;
        y[(size_t)(c * QC + t) * DINNER + h * HD + p] = f2bf(vg);
      }
      part += __shfl_xor(part, 1, 64);
      part += __shfl_xor(part, 2, 64);
      part += __shfl_xor(part, 4, 64);
      part += __shfl_xor(part, 8, 64);
      if (l15 == 0) atomicAdd(ssq + c * QC + t, part);
    }
  }
}

// ---------------------------------------------------------------------------
// Causal scores via MFMA; masked tiles pre-filled by csg_k -> early return.
// Scale already folded into q (reduce8).
// ---------------------------------------------------------------------------
__global__ __launch_bounds__(256) void scores_mfma(const u16* __restrict__ q,
                                                   const u16* __restrict__ kd,
                                                   float* __restrict__ out) {
  const int m0 = blockIdx.y * 128, n0 = blockIdx.x * 128;
  if (n0 > m0 + 127) return;  // pre-filled by csg_k
  const int tid = threadIdx.x;
  const int wave = tid >> 6, lane = tid & 63;
  const int wm = (wave >> 1) * 64, wn = (wave & 1) * 64;
  const int l15 = lane & 15, quad = lane >> 4;
  f32x4 acc[4][4] = {};
#pragma unroll
  for (int kk = 0; kk < 2; kk++) {
    short8 a[4], b[4];
#pragma unroll
    for (int i = 0; i < 4; i++) {
      a[i] = *(const short8*)(q + (size_t)(m0 + wm + i * 16 + l15) * 64 + kk * 32 + quad * 8);
      b[i] = *(const short8*)(kd + (size_t)(n0 + wn + i * 16 + l15) * 64 + kk * 32 + quad * 8);
    }
#pragma unroll
    for (int mi = 0; mi < 4; mi++)
#pragma unroll
      for (int ni = 0; ni < 4; ni++)
        acc[mi][ni] = __builtin_amdgcn_mfma_f32_16x16x32_bf16(a[mi], b[ni],
                                                              acc[mi][ni], 0, 0, 0);
  }
#pragma unroll
  for (int mi = 0; mi < 4; mi++)
#pragma unroll
    for (int r = 0; r < 4; r++) {
      int row = m0 + wm + mi * 16 + quad * 4 + r;
#pragma unroll
      for (int ni = 0; ni < 4; ni++) {
        int col = n0 + wn + ni * 16 + l15;
        float val = (col <= row) ? acc[mi][ni][r] : NEG_FILL;
        __builtin_nontemporal_store(val, out + (size_t)row * L_SEQ + col);
      }
    }
}

// ---------------------------------------------------------------------------
extern "C" void kernel_launch(void* const* d_in, const int* in_sizes, int n_in,
                              void* d_out, int out_size, void* d_ws, size_t ws_size,
                              hipStream_t stream) {
  const float* x       = (const float*)d_in[0];
  const float* W_in    = (const float*)d_in[1];
  const float* conv_w  = (const float*)d_in[2];
  const float* conv_b  = (const float*)d_in[3];
  const float* dt_bias = (const float*)d_in[4];
  const float* A_log   = (const float*)d_in[5];
  const float* Dv      = (const float*)d_in[6];
  const float* norm_w  = (const float*)d_in[7];
  const float* W_out   = (const float*)d_in[8];
  const float* W_q     = (const float*)d_in[9];
  const float* W_k     = (const float*)d_in[10];
  float* out = (float*)d_out;

  char* ws = (char*)d_ws;
  size_t off = 0;
  auto alloc = [&](size_t bytes) {
    void* p = (void*)(ws + off);
    off += (bytes + 255) & ~(size_t)255;
    return p;
  };
  u16* zx_bf    = (u16*)alloc((size_t)L_SEQ * DPROJ2 * 2);
  u16* xbc_bf   = (u16*)alloc((size_t)L_SEQ * CONVD * 2);
  float* dtsp   = (float*)alloc((size_t)L_SEQ * NH * 4);
  float* aL     = (float*)alloc((size_t)L_SEQ * NH * 4);
  u16* S        = (u16*)alloc((size_t)NC * NH * HD * DSTATE * 2);
  u16* Hinit    = (u16*)alloc((size_t)NC * NH * HD * DSTATE * 2);
  u16* G        = (u16*)alloc((size_t)NC * QC * QC * 2);
  float* ssq    = (float*)alloc((size_t)L_SEQ * 4);
  u16* y1_bf    = (u16*)alloc((size_t)L_SEQ * DINNER * 2);
  u16* kd_bf    = (u16*)alloc((size_t)L_SEQ * 64 * 2);
  u16* x_bf     = (u16*)alloc((size_t)L_SEQ * DMODEL * 2);
  u16* Wcat_bf  = (u16*)alloc((size_t)DPROJ2 * DMODEL * 2);
  u16* WoutT_bf = (u16*)alloc((size_t)DMODEL * DINNER * 2);
  u16* Wq_bf    = (u16*)alloc((size_t)64 * DMODEL * 2);
  u16* Wqo_bf   = (u16*)alloc((size_t)64 * DINNER * 2);
  u16* q_bf     = (u16*)alloc((size_t)L_SEQ * 64 * 2);
  float* Pq     = (float*)alloc((size_t)8 * L_SEQ * 64 * 4);

  // 1. all casts + W_out transpose-cast
  cast_tr_k<<<dim3(CAST_BLKS + 256), 256, 0, stream>>>(x, W_in, W_k, W_q, W_out,
                                                       x_bf, Wcat_bf, Wq_bf, WoutT_bf);
  // 2. zx gemm + wqo fold in one launch
  gemm_wqo_k<<<dim3(GEMM_BLKS + 16), 256, 0, stream>>>(x_bf, Wcat_bf, zx_bf,
                                                       Wq_bf, WoutT_bf, norm_w, Wqo_bf);
  // 3. conv+silu | k densify | dt+cumsum+ssq-zero
  conv_dt_k<<<dim3(CONVB + KDB + 256), 256, 0, stream>>>(
      zx_bf, conv_w, conv_b, xbc_bf, kd_bf, dt_bias, A_log, dtsp, aL, ssq);
  // 4. chunk states | G | masked score-tile fills (S, G bf16)
  csg_k<<<dim3(NC * NH + NC + 496), 256, 0, stream>>>(xbc_bf, dtsp, aL, S, G, out);
  // 5. inter-chunk scan (bf16 S in, bf16 Hinit out)
  state_scan_k<<<dim3(NH * HD * DSTATE / 256), 256, 0, stream>>>(S, aL, Hinit);
  // 6. y via MFMA (v1 structure + prologue trims), gated + ssq accumulation
  yout_mfma<<<dim3(NC * NH), 256, 0, stream>>>(xbc_bf, dtsp, aL, G, Hinit, Dv,
                                               zx_bf, ssq, y1_bf);
  // 7. q partials: split-K (short chain, full CU coverage)
  splitk64<<<dim3(L_SEQ / 128, 8), 256, 0, stream>>>(y1_bf, Wqo_bf, Pq, L_SEQ, DINNER);
  // 8. reduce + RMS row scale + 0.125
  reduce8_k<<<dim3(L_SEQ * 64 / 256), 256, 0, stream>>>(Pq, ssq, q_bf, L_SEQ * 64);
  // 9. causal scores (lower-triangle tiles only)
  scores_mfma<<<dim3(32, 32), 256, 0, stream>>>(q_bf, kd_bf, out);
}

// Round 8
// 215.150 us; speedup vs baseline: 1.1035x; 1.0157x over previous
//
#include <hip/hip_runtime.h>
#include <math.h>

#define L_SEQ 4096
#define DMODEL 1024
#define DINNER 1024
#define DSTATE 64
#define NH 32
#define HD 32
#define CONVD 1152   // D_INNER + 2*D_STATE
#define DPROJ2 2272  // 2*D_INNER + 2*D_STATE + NH + IDX_DIM(k fused)
#define KOFF 2208    // column offset of fused k block in zx
#define QC 128
#define NC 32

#define NEG_FILL (-1e30f)

typedef __attribute__((ext_vector_type(8))) short short8;
typedef __attribute__((ext_vector_type(4))) float f32x4;
typedef unsigned short u16;

__device__ __forceinline__ u16 f2bf(float f) {
  unsigned int u = __float_as_uint(f);
  unsigned int r = (u + 0x7fffu + ((u >> 16) & 1u)) >> 16;  // RNE
  return (u16)r;
}
__device__ __forceinline__ float bf2f(u16 b) {
  unsigned int u = ((unsigned int)b) << 16;
  return __uint_as_float(u);
}
__device__ __forceinline__ short8 pack8(float4 a, float4 b) {
  short8 v;
  v[0] = (short)f2bf(a.x); v[1] = (short)f2bf(a.y);
  v[2] = (short)f2bf(a.z); v[3] = (short)f2bf(a.w);
  v[4] = (short)f2bf(b.x); v[5] = (short)f2bf(b.y);
  v[6] = (short)f2bf(b.z); v[7] = (short)f2bf(b.w);
  return v;
}

__device__ __forceinline__ void g2l16(const void* g, void* l) {
  __builtin_amdgcn_global_load_lds(
      (const __attribute__((address_space(1))) unsigned int*)g,
      (__attribute__((address_space(3))) unsigned int*)l, 16, 0, 0);
}

// ---------------------------------------------------------------------------
// All input casts + W_out transpose-cast in ONE launch.
// ---------------------------------------------------------------------------
#define CAST_N0 (L_SEQ * DMODEL / 8)      // 524288
#define CAST_N1 (2208 * DMODEL / 8)       // 282624
#define CAST_N2 (64 * DMODEL / 8)         // 8192
#define CAST_TOTAL (CAST_N0 + CAST_N1 + 2 * CAST_N2)  // 823296 = 3216*256
#define CAST_BLKS (CAST_TOTAL / 256)      // 3216
__global__ __launch_bounds__(256) void cast_tr_k(const float* __restrict__ x,
                                                 const float* __restrict__ W_in,
                                                 const float* __restrict__ W_k,
                                                 const float* __restrict__ W_q,
                                                 const float* __restrict__ W_out,
                                                 u16* __restrict__ x_bf,
                                                 u16* __restrict__ Wcat,
                                                 u16* __restrict__ Wq_bf,
                                                 u16* __restrict__ WoutT) {
  __shared__ float tile[64][65];
  int bid = blockIdx.x;
  if (bid < CAST_BLKS) {
    int gid = bid * 256 + threadIdx.x;
    const float* src;
    u16* dst;
    int i;
    if (gid < CAST_N0) { src = x; dst = x_bf; i = gid; }
    else if (gid < CAST_N0 + CAST_N1) { src = W_in; dst = Wcat; i = gid - CAST_N0; }
    else if (gid < CAST_N0 + CAST_N1 + CAST_N2) {
      src = W_k; dst = Wcat + (size_t)2208 * DMODEL; i = gid - CAST_N0 - CAST_N1;
    } else { src = W_q; dst = Wq_bf; i = gid - CAST_N0 - CAST_N1 - CAST_N2; }
    i *= 8;
    float4 f0 = *(const float4*)(src + i);
    float4 f1 = *(const float4*)(src + i + 4);
    *(short8*)(dst + i) = pack8(f0, f1);
    return;
  }
  // transpose-cast blocks: WoutT[j, m] = bf16(W_out[m, j]), 64x64 tiles
  bid -= CAST_BLKS;
  int bx = bid & 15, by = bid >> 4;
  int tx = threadIdx.x & 63, ty = threadIdx.x >> 6;
#pragma unroll
  for (int k = 0; k < 16; k++) {
    int r = ty + k * 4;
    tile[r][tx] = W_out[(size_t)(by * 64 + r) * 1024 + bx * 64 + tx];
  }
  __syncthreads();
#pragma unroll
  for (int k = 0; k < 16; k++) {
    int r = ty + k * 4;
    WoutT[(size_t)(bx * 64 + r) * 1024 + by * 64 + tx] = f2bf(tile[tx][r]);
  }
}

// ---------------------------------------------------------------------------
// Main GEMM (blocks [0,576)): zx = x @ [W_in; W_k]^T, 128x128 tile, BK=64.
// Blocks [576, 592): Wqo[i,j] = (W_q @ W_out)[i,j] * norm_w[j].
// (Epilogue kept branch-free per R6 post-mortem: silu/kd folding cost +13us.)
// ---------------------------------------------------------------------------
#define GEMM_BLKS 576  // (4096/128) * (2304/128) = 32 * 18
__global__ __launch_bounds__(256) void gemm_wqo_k(const u16* __restrict__ A,
                                                  const u16* __restrict__ B,
                                                  u16* __restrict__ Cbf,
                                                  const u16* __restrict__ Wq,
                                                  const u16* __restrict__ WoutT,
                                                  const float* __restrict__ nw,
                                                  u16* __restrict__ Wqo) {
  __shared__ u16 As[128 * 64];  // 16 KB
  __shared__ u16 Bs[128 * 64];  // 16 KB
  const int tid = threadIdx.x;
  const int wave = tid >> 6, lane = tid & 63;
  const int l15 = lane & 15, quad = lane >> 4;
  const int wg = blockIdx.x;
  if (wg >= GEMM_BLKS) {  // ---- wqo branch ----
    const int j0 = (wg - GEMM_BLKS) * 64;
    f32x4 acc[4] = {};
    for (int kk = 0; kk < 32; kk++) {
      short8 b = *(const short8*)(WoutT + (size_t)(j0 + wave * 16 + l15) * 1024 + kk * 32 + quad * 8);
#pragma unroll
      for (int mi = 0; mi < 4; mi++) {
        short8 a = *(const short8*)(Wq + (size_t)(mi * 16 + l15) * 1024 + kk * 32 + quad * 8);
        acc[mi] = __builtin_amdgcn_mfma_f32_16x16x32_bf16(a, b, acc[mi], 0, 0, 0);
      }
    }
    int col = j0 + wave * 16 + l15;
    float w = nw[col];
#pragma unroll
    for (int mi = 0; mi < 4; mi++)
#pragma unroll
      for (int r = 0; r < 4; r++) {
        int i = mi * 16 + quad * 4 + r;
        Wqo[(size_t)i * 1024 + col] = f2bf(acc[mi][r] * w);
      }
    return;
  }
  // ---- main gemm ----
  const int N = DPROJ2, K = DMODEL;
  const int m0 = (wg & 31) * 128, n0 = (wg >> 5) * 128;
  const int wm = (wave >> 1) * 64, wn = (wave & 1) * 64;

  const u16* aptr[4];
  const u16* bptr[4];
  char *ldsA[4], *ldsB[4];
#pragma unroll
  for (int b = 0; b < 4; b++) {
    int ch = b * 256 + tid;
    int row = ch >> 3, q = (ch & 7) ^ (row & 7);
    aptr[b] = A + (size_t)(m0 + row) * K + q * 8;
    int bn = min(n0 + row, N - 1);
    bptr[b] = B + (size_t)bn * K + q * 8;
    ldsA[b] = (char*)As + b * 4096 + wave * 1024;
    ldsB[b] = (char*)Bs + b * 4096 + wave * 1024;
  }

  int offA[2][4], offB[2][4];
#pragma unroll
  for (int kk = 0; kk < 2; kk++)
#pragma unroll
    for (int i = 0; i < 4; i++) {
      int ra = wm + i * 16 + l15;
      offA[kk][i] = ra * 64 + ((kk * 4 + quad) ^ (ra & 7)) * 8;
      int rb = wn + i * 16 + l15;
      offB[kk][i] = rb * 64 + ((kk * 4 + quad) ^ (rb & 7)) * 8;
    }

  f32x4 acc[4][4] = {};
  for (int k0 = 0; k0 < K; k0 += 64) {
#pragma unroll
    for (int b = 0; b < 4; b++) g2l16(aptr[b] + k0, ldsA[b]);
#pragma unroll
    for (int b = 0; b < 4; b++) g2l16(bptr[b] + k0, ldsB[b]);
    __builtin_amdgcn_s_waitcnt(0);
    __syncthreads();
#pragma unroll
    for (int kk = 0; kk < 2; kk++) {
      short8 af[4], bfr[4];
#pragma unroll
      for (int i = 0; i < 4; i++) af[i] = *(const short8*)(As + offA[kk][i]);
#pragma unroll
      for (int j = 0; j < 4; j++) bfr[j] = *(const short8*)(Bs + offB[kk][j]);
#pragma unroll
      for (int mi = 0; mi < 4; mi++)
#pragma unroll
        for (int ni = 0; ni < 4; ni++)
          acc[mi][ni] = __builtin_amdgcn_mfma_f32_16x16x32_bf16(af[mi], bfr[ni],
                                                                acc[mi][ni], 0, 0, 0);
    }
    __syncthreads();
  }
#pragma unroll
  for (int mi = 0; mi < 4; mi++)
#pragma unroll
    for (int r = 0; r < 4; r++) {
      int grow = m0 + wm + mi * 16 + quad * 4 + r;
#pragma unroll
      for (int ni = 0; ni < 4; ni++) {
        int gcol = n0 + wn + ni * 16 + l15;
        if (gcol < N) Cbf[(size_t)grow * N + gcol] = f2bf(acc[mi][ni][r]);
      }
    }
}

// ---------------------------------------------------------------------------
// Split-K bf16 MFMA (N=64): P[ks][M,64] = A[M,Kslab] * B[64,Kslab]^T
// ---------------------------------------------------------------------------
__global__ __launch_bounds__(256) void splitk64(const u16* __restrict__ A,
                                                const u16* __restrict__ B,
                                                float* __restrict__ P,
                                                int M, int K) {
  __shared__ u16 As[128 * 32];
  __shared__ u16 Bs[64 * 32];
  const int tid = threadIdx.x;
  const int wave = tid >> 6, lane = tid & 63;
  const int m0 = blockIdx.x * 128;
  const int ks = blockIdx.y;
  const int wm = (wave >> 1) * 64, wn = (wave & 1) * 32;
  const int l15 = lane & 15, quad = lane >> 4;

  const int c0 = tid, c1 = 256 + tid;
  const int r0 = c0 >> 2, q0 = (c0 & 3) ^ ((r0 >> 1) & 3);
  const int r1 = c1 >> 2, q1 = (c1 & 3) ^ ((r1 >> 1) & 3);
  const int rb = tid >> 2, qb = (tid & 3) ^ ((rb >> 1) & 3);
  const u16* a0 = A + (size_t)(m0 + r0) * K + q0 * 8;
  const u16* a1 = A + (size_t)(m0 + r1) * K + q1 * 8;
  const u16* bptr = B + (size_t)rb * K + qb * 8;
  char* ldsA0 = (char*)As + wave * 1024;
  char* ldsA1 = (char*)As + 4096 + wave * 1024;
  char* ldsB = (char*)Bs + wave * 1024;

  int offA[4], offB[2];
#pragma unroll
  for (int i = 0; i < 4; i++) {
    int ra = wm + i * 16 + l15;
    offA[i] = ra * 32 + (quad ^ ((ra >> 1) & 3)) * 8;
  }
#pragma unroll
  for (int j = 0; j < 2; j++) {
    int rr = wn + j * 16 + l15;
    offB[j] = rr * 32 + (quad ^ ((rr >> 1) & 3)) * 8;
  }

  f32x4 acc[4][2] = {};
  const int kbeg = ks * 128;
  for (int k0 = kbeg; k0 < kbeg + 128; k0 += 32) {
    g2l16(a0 + k0, ldsA0);
    g2l16(a1 + k0, ldsA1);
    g2l16(bptr + k0, ldsB);
    __builtin_amdgcn_s_waitcnt(0);
    __syncthreads();
    short8 af[4], bfr[2];
#pragma unroll
    for (int i = 0; i < 4; i++) af[i] = *(const short8*)(As + offA[i]);
#pragma unroll
    for (int j = 0; j < 2; j++) bfr[j] = *(const short8*)(Bs + offB[j]);
#pragma unroll
    for (int mi = 0; mi < 4; mi++)
#pragma unroll
      for (int ni = 0; ni < 2; ni++)
        acc[mi][ni] = __builtin_amdgcn_mfma_f32_16x16x32_bf16(af[mi], bfr[ni],
                                                              acc[mi][ni], 0, 0, 0);
    __syncthreads();
  }
  float* Pp = P + (size_t)ks * M * 64;
#pragma unroll
  for (int mi = 0; mi < 4; mi++)
#pragma unroll
    for (int r = 0; r < 4; r++) {
      int grow = m0 + wm + mi * 16 + quad * 4 + r;
#pragma unroll
      for (int ni = 0; ni < 2; ni++)
        Pp[(size_t)grow * 64 + wn + ni * 16 + l15] = acc[mi][ni][r];
    }
}

// reduce split-K partials + folded RMSNorm row scale + 1/sqrt(64) score scale.
__global__ __launch_bounds__(256) void reduce8_k(const float* __restrict__ P,
                                                 const float* __restrict__ ssq,
                                                 u16* __restrict__ out, int n) {
  int i = blockIdx.x * 256 + threadIdx.x;
  if (i >= n) return;
  float s = 0.f;
#pragma unroll
  for (int ks = 0; ks < 8; ks++) s += P[(size_t)ks * n + i];
  float sc = rsqrtf(ssq[i >> 6] * (1.f / 1024.f) + 1e-5f) * 0.125f;
  out[i] = f2bf(s * sc);
}

// ---------------------------------------------------------------------------
// conv1d+SiLU (blocks [0,2304)), k-densify (blocks [2304,2432)),
// dt softplus + cumsum + ssq zero (blocks [2432,2688)).
// dtsp/aL now stored TRANSPOSED [h][t] -> all writes/reads coalesced.
// ---------------------------------------------------------------------------
#define CONVB 2304  // 256 t-blocks * 9 cg-blocks
#define KDB 128
__global__ __launch_bounds__(256) void conv_dt_k(const u16* __restrict__ zx,
                                                 const float* __restrict__ cw,
                                                 const float* __restrict__ cb,
                                                 u16* __restrict__ xbc,
                                                 u16* __restrict__ kd,
                                                 const float* __restrict__ dt_bias,
                                                 const float* __restrict__ A_log,
                                                 float* __restrict__ dtsp,
                                                 float* __restrict__ aL,
                                                 float* __restrict__ ssq) {
  int bid = blockIdx.x, tid = threadIdx.x;
  if (bid < CONVB) {
    int tblk = bid / 9, cgb = bid - tblk * 9;
    int t = tblk * 16 + (tid >> 4);
    int c0 = (cgb * 16 + (tid & 15)) * 8;
    float acc[8];
#pragma unroll
    for (int j = 0; j < 8; j++) acc[j] = cb[c0 + j];
    float wv[8][4];
#pragma unroll
    for (int j = 0; j < 8; j++) {
      float4 w4 = *(const float4*)(cw + (c0 + j) * 4);
      wv[j][0] = w4.x; wv[j][1] = w4.y; wv[j][2] = w4.z; wv[j][3] = w4.w;
    }
#pragma unroll
    for (int k = 0; k < 4; k++) {
      int s = t - 3 + k;
      if (s >= 0) {
        short8 v = *(const short8*)(zx + (size_t)s * DPROJ2 + DINNER + c0);
#pragma unroll
        for (int j = 0; j < 8; j++) acc[j] += bf2f((u16)v[j]) * wv[j][k];
      }
    }
    short8 o;
#pragma unroll
    for (int j = 0; j < 8; j++) o[j] = (short)f2bf(acc[j] / (1.f + expf(-acc[j])));
    *(short8*)(xbc + (size_t)t * CONVD + c0) = o;
    return;
  }
  if (bid < CONVB + KDB) {  // densify k: kd[t, 0..64) = zx[t, KOFF..KOFF+64)
    int gid = (bid - CONVB) * 256 + tid;
    int t = gid >> 3, c0 = (gid & 7) * 8;
    *(short8*)(kd + (size_t)t * 64 + c0) =
        *(const short8*)(zx + (size_t)t * DPROJ2 + KOFF + c0);
    return;
  }
  int dblk = bid - CONVB - KDB;  // 0..255
  if (tid < 16) ssq[dblk * 16 + tid] = 0.f;
  int w = tid >> 6, lane = tid & 63;
  int idx = dblk * 4 + w;  // 0..1023
  int h = idx & 31, c = idx >> 5;
  float negA = -expf(A_log[h]);
  float bias = dt_bias[h];
  float carry = 0.f;
#pragma unroll
  for (int seg = 0; seg < 2; seg++) {
    int t = c * QC + seg * 64 + lane;
    float xv = bf2f(zx[(size_t)t * DPROJ2 + 2176 + h]) + bias;
    float sp = (xv > 20.f) ? xv : log1pf(expf(xv));
    dtsp[(size_t)h * L_SEQ + t] = sp;          // coalesced [h][t]
    float v = sp * negA;
#pragma unroll
    for (int off = 1; off < 64; off <<= 1) {
      float u = __shfl_up(v, off, 64);
      if (lane >= off) v += u;
    }
    aL[(size_t)h * L_SEQ + t] = carry + v;     // coalesced [h][t]
    carry += __shfl(v, 63, 64);
  }
}

// ---------------------------------------------------------------------------
// Chunk states via MFMA (blocks [0,1024)), G = C·B^T (blocks [1024,1056)),
// fully-masked score-tile fills (blocks [1056,1552)). S and G stored bf16.
// ---------------------------------------------------------------------------
__global__ __launch_bounds__(256) void csg_k(const u16* __restrict__ xbc,
                                             const float* __restrict__ dtsp,
                                             const float* __restrict__ aL,
                                             u16* __restrict__ S,
                                             u16* __restrict__ G,
                                             float* __restrict__ out) {
  int tid = threadIdx.x;
  const int wave = tid >> 6, lane = tid & 63;
  const int l15 = lane & 15, quad = lane >> 4;
  __shared__ __align__(16) u16 sXs[32 * 136];
  __shared__ __align__(16) u16 sBT[64 * 136];
  __shared__ float scoef[QC];
  if (blockIdx.x < (unsigned)(NC * NH)) {
    int h = blockIdx.x & 31, c = blockIdx.x >> 5;
    if (tid < QC) {
      float aend = aL[(size_t)h * L_SEQ + c * QC + QC - 1];
      float a = aL[(size_t)h * L_SEQ + c * QC + tid];        // coalesced
      scoef[tid] = expf(aend - a) * dtsp[(size_t)h * L_SEQ + c * QC + tid];
    }
    __syncthreads();
    for (int j = tid; j < 32 * QC / 8; j += 256) {   // scaled X^T
      int s = j & 127, p0 = (j >> 7) * 8;
      short8 v = *(const short8*)(xbc + (size_t)(c * QC + s) * CONVD + h * HD + p0);
      float cf = scoef[s];
#pragma unroll
      for (int e = 0; e < 8; e++) sXs[(p0 + e) * 136 + s] = f2bf(cf * bf2f((u16)v[e]));
    }
    for (int j = tid; j < 64 * QC / 8; j += 256) {   // B^T
      int s = j & 127, n0 = (j >> 7) * 8;
      short8 v = *(const short8*)(xbc + (size_t)(c * QC + s) * CONVD + DINNER + n0);
#pragma unroll
      for (int e = 0; e < 8; e++) sBT[(n0 + e) * 136 + s] = (u16)v[e];
    }
    __syncthreads();
    f32x4 acc[2] = {};
#pragma unroll
    for (int kk = 0; kk < 4; kk++) {
      short8 b = *(const short8*)(sBT + (wave * 16 + l15) * 136 + kk * 32 + quad * 8);
#pragma unroll
      for (int i = 0; i < 2; i++) {
        short8 a = *(const short8*)(sXs + (i * 16 + l15) * 136 + kk * 32 + quad * 8);
        acc[i] = __builtin_amdgcn_mfma_f32_16x16x32_bf16(a, b, acc[i], 0, 0, 0);
      }
    }
    u16* Sb = S + ((size_t)c * 32 + h) * 2048;
#pragma unroll
    for (int i = 0; i < 2; i++)
#pragma unroll
      for (int r = 0; r < 4; r++) {
        int p = i * 16 + quad * 4 + r;
        Sb[p * 64 + wave * 16 + l15] = f2bf(acc[i][r]);
      }
    return;
  }
  if (blockIdx.x < (unsigned)(NC * NH + NC)) {
    // G = C B^T, direct bf16 global frag loads
    int c = blockIdx.x - NC * NH;
    const int wm = (wave >> 1) * 64, wn = (wave & 1) * 64;
    f32x4 acc[4][4] = {};
#pragma unroll
    for (int kk = 0; kk < 2; kk++) {
      short8 a[4], b[4];
#pragma unroll
      for (int i = 0; i < 4; i++) {
        int t = wm + i * 16 + l15;
        a[i] = *(const short8*)(xbc + (size_t)(c * QC + t) * CONVD + DINNER + DSTATE + kk * 32 + quad * 8);
        int s = wn + i * 16 + l15;
        b[i] = *(const short8*)(xbc + (size_t)(c * QC + s) * CONVD + DINNER + kk * 32 + quad * 8);
      }
#pragma unroll
      for (int mi = 0; mi < 4; mi++)
#pragma unroll
        for (int ni = 0; ni < 4; ni++)
          acc[mi][ni] = __builtin_amdgcn_mfma_f32_16x16x32_bf16(a[mi], b[ni],
                                                                acc[mi][ni], 0, 0, 0);
    }
    u16* Gb = G + (size_t)c * QC * QC;
#pragma unroll
    for (int mi = 0; mi < 4; mi++)
#pragma unroll
      for (int r = 0; r < 4; r++) {
        int t = wm + mi * 16 + quad * 4 + r;
#pragma unroll
        for (int ni = 0; ni < 4; ni++)
          Gb[(size_t)t * QC + wn + ni * 16 + l15] = f2bf(acc[mi][ni][r]);
      }
    return;
  }
  // fully-masked score tiles: enumerate {(by,bx): bx > by} via 16x31 rect
  int f = blockIdx.x - (NC * NH + NC);  // 0..495
  int u = f / 31, v = f - u * 31;
  int by, bx;
  if (v >= u) { by = u; bx = v + 1; }
  else { by = 31 - u; bx = 32 - u + v; }
  int m0 = by * 128, n0 = bx * 128;
  f32x4 fl = {NEG_FILL, NEG_FILL, NEG_FILL, NEG_FILL};
  for (int i = tid; i < 128 * 32; i += 256) {
    int row = i >> 5, c4 = (i & 31) << 2;
    __builtin_nontemporal_store(fl, (f32x4*)(out + (size_t)(m0 + row) * L_SEQ + n0 + c4));
  }
}

// ---------------------------------------------------------------------------
// Inter-chunk scan; S bf16 in, fp32 accumulate, Hinit bf16 out.
// ---------------------------------------------------------------------------
__global__ __launch_bounds__(256) void state_scan_k(const u16* __restrict__ S,
                                                    const float* __restrict__ aL,
                                                    u16* __restrict__ Hinit) {
  int idx = blockIdx.x * 256 + threadIdx.x;
  int h = idx >> 11, rem = idx & 2047;
  float E = 0.f;
#pragma unroll
  for (int c = 0; c < NC; c++) {
    size_t o = ((size_t)c * 32 + h) * 2048 + rem;
    Hinit[o] = f2bf(E);
    float dec = expf(aL[(size_t)h * L_SEQ + c * QC + QC - 1]);
    E = E * dec + bf2f(S[o]);
  }
}

// ---------------------------------------------------------------------------
// yout: 1024 blocks, full chunk; prologue sa/sd loads now coalesced ([h][t]
// layout), se=exp(a) once per row, silu(z) gate staged from vectorized loads.
// ---------------------------------------------------------------------------
__global__ __launch_bounds__(256) void yout_mfma(const u16* __restrict__ xbc,
                                                 const float* __restrict__ dtsp,
                                                 const float* __restrict__ aL,
                                                 const u16* __restrict__ G,
                                                 const u16* __restrict__ Hinit,
                                                 const float* __restrict__ Dv,
                                                 const u16* __restrict__ zx,
                                                 float* __restrict__ ssq,
                                                 u16* __restrict__ y) {
  int h = blockIdx.x & 31, c = blockIdx.x >> 5;
  int tid = threadIdx.x;
  __shared__ __align__(16) u16 sXT[32 * 136];
  __shared__ float sa[QC];
  __shared__ float sd[QC];
  __shared__ float se[QC];
  __shared__ float sgate[QC][32];

  if (tid < QC) {
    float a_ = aL[(size_t)h * L_SEQ + c * QC + tid];   // coalesced
    sa[tid] = a_;
    se[tid] = expf(a_);
    sd[tid] = dtsp[(size_t)h * L_SEQ + c * QC + tid];  // coalesced
  }
  for (int j = tid; j < 512; j += 256) {  // silu(z) gate, vectorized loads
    int t = j >> 2, p0 = (j & 3) * 8;
    short8 v = *(const short8*)(zx + (size_t)(c * QC + t) * DPROJ2 + h * HD + p0);
#pragma unroll
    for (int e = 0; e < 8; e++) {
      float z = bf2f((u16)v[e]);
      sgate[t][p0 + e] = z / (1.f + expf(-z));
    }
  }
  for (int j = tid; j < 32 * QC / 8; j += 256) {
    int t = j & 127, p0 = (j >> 7) * 8;
    short8 v = *(const short8*)(xbc + (size_t)(c * QC + t) * CONVD + h * HD + p0);
#pragma unroll
    for (int e = 0; e < 8; e++) sXT[(p0 + e) * 136 + t] = (u16)v[e];
  }
  __syncthreads();

  const int wave = tid >> 6, lane = tid & 63;
  const int l15 = lane & 15, quad = lane >> 4;
  f32x4 acc1[2][2] = {};
  f32x4 acc2[2][2] = {};

#pragma unroll
  for (int kk = 0; kk < 4; kk++) {
    short8 b[2];
#pragma unroll
    for (int j = 0; j < 2; j++)
      b[j] = *(const short8*)(sXT + (j * 16 + l15) * 136 + kk * 32 + quad * 8);
#pragma unroll
    for (int i = 0; i < 2; i++) {
      int rmax = wave * 32 + i * 16 + 15;
      if (kk * 32 > rmax) continue;
      int m = wave * 32 + i * 16 + l15;
      float am = sa[m];
      short8 g8 = *(const short8*)(G + (size_t)c * QC * QC + (size_t)m * QC + kk * 32 + quad * 8);
      int s0 = kk * 32 + quad * 8;
      short8 a;
#pragma unroll
      for (int j2 = 0; j2 < 8; j2++) {
        int s = s0 + j2;
        float w = 0.f;
        if (s <= m) w = expf(am - sa[s]) * sd[s] * bf2f((u16)g8[j2]);
        a[j2] = (short)f2bf(w);
      }
#pragma unroll
      for (int j = 0; j < 2; j++)
        acc1[i][j] = __builtin_amdgcn_mfma_f32_16x16x32_bf16(a, b[j], acc1[i][j], 0, 0, 0);
    }
  }

  const u16* Hbase = Hinit + ((size_t)c * 32 + h) * 2048;
#pragma unroll
  for (int kk = 0; kk < 2; kk++) {
    short8 b[2];
#pragma unroll
    for (int j = 0; j < 2; j++)
      b[j] = *(const short8*)(Hbase + (size_t)(j * 16 + l15) * 64 + kk * 32 + quad * 8);
#pragma unroll
    for (int i = 0; i < 2; i++) {
      int t = wave * 32 + i * 16 + l15;
      short8 a = *(const short8*)(xbc + (size_t)(c * QC + t) * CONVD + DINNER + DSTATE + kk * 32 + quad * 8);
#pragma unroll
      for (int j = 0; j < 2; j++)
        acc2[i][j] = __builtin_amdgcn_mfma_f32_16x16x32_bf16(a, b[j], acc2[i][j], 0, 0, 0);
    }
  }

  float Dh = Dv[h];
#pragma unroll
  for (int i = 0; i < 2; i++) {
#pragma unroll
    for (int r = 0; r < 4; r++) {
      int t = wave * 32 + i * 16 + quad * 4 + r;
      float et = se[t];
      float part = 0.f;
#pragma unroll
      for (int j = 0; j < 2; j++) {
        int p = j * 16 + l15;
        float xv = bf2f(sXT[p * 136 + t]);
        float val = acc1[i][j][r] + et * acc2[i][j][r] + Dh * xv;
        float vg = val * sgate[t][p];
        part += vg * vg;
        y[(size_t)(c * QC + t) * DINNER + h * HD + p] = f2bf(vg);
      }
      part += __shfl_xor(part, 1, 64);
      part += __shfl_xor(part, 2, 64);
      part += __shfl_xor(part, 4, 64);
      part += __shfl_xor(part, 8, 64);
      if (l15 == 0) atomicAdd(ssq + c * QC + t, part);
    }
  }
}

// ---------------------------------------------------------------------------
// Causal scores via MFMA; masked tiles pre-filled by csg_k -> early return.
// Scale already folded into q (reduce8).
// ---------------------------------------------------------------------------
__global__ __launch_bounds__(256) void scores_mfma(const u16* __restrict__ q,
                                                   const u16* __restrict__ kd,
                                                   float* __restrict__ out) {
  const int m0 = blockIdx.y * 128, n0 = blockIdx.x * 128;
  if (n0 > m0 + 127) return;  // pre-filled by csg_k
  const int tid = threadIdx.x;
  const int wave = tid >> 6, lane = tid & 63;
  const int wm = (wave >> 1) * 64, wn = (wave & 1) * 64;
  const int l15 = lane & 15, quad = lane >> 4;
  f32x4 acc[4][4] = {};
#pragma unroll
  for (int kk = 0; kk < 2; kk++) {
    short8 a[4], b[4];
#pragma unroll
    for (int i = 0; i < 4; i++) {
      a[i] = *(const short8*)(q + (size_t)(m0 + wm + i * 16 + l15) * 64 + kk * 32 + quad * 8);
      b[i] = *(const short8*)(kd + (size_t)(n0 + wn + i * 16 + l15) * 64 + kk * 32 + quad * 8);
    }
#pragma unroll
    for (int mi = 0; mi < 4; mi++)
#pragma unroll
      for (int ni = 0; ni < 4; ni++)
        acc[mi][ni] = __builtin_amdgcn_mfma_f32_16x16x32_bf16(a[mi], b[ni],
                                                              acc[mi][ni], 0, 0, 0);
  }
#pragma unroll
  for (int mi = 0; mi < 4; mi++)
#pragma unroll
    for (int r = 0; r < 4; r++) {
      int row = m0 + wm + mi * 16 + quad * 4 + r;
#pragma unroll
      for (int ni = 0; ni < 4; ni++) {
        int col = n0 + wn + ni * 16 + l15;
        float val = (col <= row) ? acc[mi][ni][r] : NEG_FILL;
        __builtin_nontemporal_store(val, out + (size_t)row * L_SEQ + col);
      }
    }
}

// ---------------------------------------------------------------------------
extern "C" void kernel_launch(void* const* d_in, const int* in_sizes, int n_in,
                              void* d_out, int out_size, void* d_ws, size_t ws_size,
                              hipStream_t stream) {
  const float* x       = (const float*)d_in[0];
  const float* W_in    = (const float*)d_in[1];
  const float* conv_w  = (const float*)d_in[2];
  const float* conv_b  = (const float*)d_in[3];
  const float* dt_bias = (const float*)d_in[4];
  const float* A_log   = (const float*)d_in[5];
  const float* Dv      = (const float*)d_in[6];
  const float* norm_w  = (const float*)d_in[7];
  const float* W_out   = (const float*)d_in[8];
  const float* W_q     = (const float*)d_in[9];
  const float* W_k     = (const float*)d_in[10];
  float* out = (float*)d_out;

  char* ws = (char*)d_ws;
  size_t off = 0;
  auto alloc = [&](size_t bytes) {
    void* p = (void*)(ws + off);
    off += (bytes + 255) & ~(size_t)255;
    return p;
  };
  u16* zx_bf    = (u16*)alloc((size_t)L_SEQ * DPROJ2 * 2);
  u16* xbc_bf   = (u16*)alloc((size_t)L_SEQ * CONVD * 2);
  float* dtsp   = (float*)alloc((size_t)L_SEQ * NH * 4);   // [h][t] transposed
  float* aL     = (float*)alloc((size_t)L_SEQ * NH * 4);   // [h][t] transposed
  u16* S        = (u16*)alloc((size_t)NC * NH * HD * DSTATE * 2);
  u16* Hinit    = (u16*)alloc((size_t)NC * NH * HD * DSTATE * 2);
  u16* G        = (u16*)alloc((size_t)NC * QC * QC * 2);
  float* ssq    = (float*)alloc((size_t)L_SEQ * 4);
  u16* y1_bf    = (u16*)alloc((size_t)L_SEQ * DINNER * 2);
  u16* kd_bf    = (u16*)alloc((size_t)L_SEQ * 64 * 2);
  u16* x_bf     = (u16*)alloc((size_t)L_SEQ * DMODEL * 2);
  u16* Wcat_bf  = (u16*)alloc((size_t)DPROJ2 * DMODEL * 2);
  u16* WoutT_bf = (u16*)alloc((size_t)DMODEL * DINNER * 2);
  u16* Wq_bf    = (u16*)alloc((size_t)64 * DMODEL * 2);
  u16* Wqo_bf   = (u16*)alloc((size_t)64 * DINNER * 2);
  u16* q_bf     = (u16*)alloc((size_t)L_SEQ * 64 * 2);
  float* Pq     = (float*)alloc((size_t)8 * L_SEQ * 64 * 4);

  // 1. all casts + W_out transpose-cast
  cast_tr_k<<<dim3(CAST_BLKS + 256), 256, 0, stream>>>(x, W_in, W_k, W_q, W_out,
                                                       x_bf, Wcat_bf, Wq_bf, WoutT_bf);
  // 2. zx gemm + wqo fold in one launch
  gemm_wqo_k<<<dim3(GEMM_BLKS + 16), 256, 0, stream>>>(x_bf, Wcat_bf, zx_bf,
                                                       Wq_bf, WoutT_bf, norm_w, Wqo_bf);
  // 3. conv+silu | k densify | dt+cumsum+ssq-zero  ([h][t] layouts)
  conv_dt_k<<<dim3(CONVB + KDB + 256), 256, 0, stream>>>(
      zx_bf, conv_w, conv_b, xbc_bf, kd_bf, dt_bias, A_log, dtsp, aL, ssq);
  // 4. chunk states | G | masked score-tile fills (S, G bf16)
  csg_k<<<dim3(NC * NH + NC + 496), 256, 0, stream>>>(xbc_bf, dtsp, aL, S, G, out);
  // 5. inter-chunk scan (bf16 S in, bf16 Hinit out)
  state_scan_k<<<dim3(NH * HD * DSTATE / 256), 256, 0, stream>>>(S, aL, Hinit);
  // 6. y via MFMA (coalesced prologue), gated + ssq accumulation
  yout_mfma<<<dim3(NC * NH), 256, 0, stream>>>(xbc_bf, dtsp, aL, G, Hinit, Dv,
                                               zx_bf, ssq, y1_bf);
  // 7. q partials: split-K (short chain, full CU coverage)
  splitk64<<<dim3(L_SEQ / 128, 8), 256, 0, stream>>>(y1_bf, Wqo_bf, Pq, L_SEQ, DINNER);
  // 8. reduce + RMS row scale + 0.125
  reduce8_k<<<dim3(L_SEQ * 64 / 256), 256, 0, stream>>>(Pq, ssq, q_bf, L_SEQ * 64);
  // 9. causal scores (lower-triangle tiles only)
  scores_mfma<<<dim3(32, 32), 256, 0, stream>>>(q_bf, kd_bf, out);
}